// Round 1
// 2358.838 us; speedup vs baseline: 1.1142x; 1.1142x over previous
//
#include <hip/hip_runtime.h>
#include <math.h>

#define B_      2
#define N_      2048
#define DIM_    1024
#define ROWS_   4096      // B*N
#define DCOND_  4096
#define DFF_    2730
#define DFF1_   5460
#define KF_     1056      // fourier K padded (1025 -> 1056)
#define KM_     2752      // geglu-mid K padded (2730 -> 2752)
#define SCALE_  0.125f
#define TWO_PI_ 6.28318530717958647692f

#define KSTR_   72        // K-tile LDS row stride (shorts)
#define VSTR_   72        // V^T-tile LDS row stride
#define PSTR_   68        // P-tile LDS row stride

typedef __attribute__((ext_vector_type(8))) short bfx8;   // 8 bf16 = 4 VGPR
typedef __attribute__((ext_vector_type(4))) float fx4;    // MFMA accum

__device__ __forceinline__ float b2f(unsigned short u) {
  return __uint_as_float(((unsigned)u) << 16);
}
__device__ __forceinline__ unsigned short f2b(float f) {  // RNE
  unsigned x = __float_as_uint(f);
  return (unsigned short)((x + 0x7FFF + ((x >> 16) & 1)) >> 16);
}

// ---------------------------------------------------------------- fourier -> bf16 [4096][1056], zero-padded
__global__ __launch_bounds__(256) void fourier_kernel(const float* __restrict__ times,
                                                      const float* __restrict__ fw,
                                                      unsigned short* __restrict__ F) {
  int r = blockIdx.x;
  float tv = times[r];
  unsigned short* Fr = F + (size_t)r * KF_;
  for (int c = threadIdx.x; c < KF_; c += 256) {
    float v;
    if (c == 0)          v = tv;
    else if (c <= 512)   v = sinf(tv * fw[c - 1] * TWO_PI_);
    else if (c <= 1024)  v = cosf(tv * fw[c - 513] * TWO_PI_);
    else                 v = 0.f;
    Fr[c] = f2b(v);
  }
}

// ---------------------------------------------------------------- weight transpose: W f32 [K][N] -> WT bf16 [N][KP]
__global__ __launch_bounds__(256) void transpose_w(const float* __restrict__ W,
                                                   unsigned short* __restrict__ WT,
                                                   int K, int N, int KP) {
  __shared__ float t[32][33];
  int tx = threadIdx.x, ty = threadIdx.y;    // 32 x 8
  int k0 = blockIdx.x * 32, n0 = blockIdx.y * 32;
#pragma unroll
  for (int i = 0; i < 4; ++i) {
    int k = k0 + ty + i * 8, n = n0 + tx;
    t[ty + i * 8][tx] = (k < K && n < N) ? W[(size_t)k * N + n] : 0.f;
  }
  __syncthreads();
#pragma unroll
  for (int i = 0; i < 4; ++i) {
    int n = n0 + ty + i * 8;
    if (n < N) WT[(size_t)n * KP + k0 + tx] = f2b(t[tx][ty + i * 8]);
  }
}

// ---------------------------------------------------------------- MFMA GEMM (global_load_lds width-16 staging, m97 structure)
__global__ __launch_bounds__(256) void mfma_gemm(const unsigned short* __restrict__ A,
                                                 const unsigned short* __restrict__ BT,
                                                 const float* __restrict__ bias,
                                                 void* __restrict__ Cout,
                                                 int K, int Nc, int mode, int out_bf) {
  __shared__ unsigned short As[128 * 32];
  __shared__ unsigned short Bs[128 * 32];
  int tid = threadIdx.x;
  int wave = tid >> 6, lane = tid & 63;
  int bm = blockIdx.y * 128, bn = blockIdx.x * 128;
  int wm = (wave >> 1) * 64, wn = (wave & 1) * 64;
  int lr = lane >> 4, lc = lane & 15;
  fx4 acc[4][4];
#pragma unroll
  for (int i = 0; i < 4; ++i)
#pragma unroll
    for (int j = 0; j < 4; ++j) acc[i][j] = (fx4){0.f, 0.f, 0.f, 0.f};

  for (int k0 = 0; k0 < K; k0 += 32) {
    // async global -> LDS, 16B per lane, linear LDS dest (wave base + lane*16)
#pragma unroll
    for (int i = 0; i < 2; ++i) {
      int c = tid + i * 256;
      int row = c >> 2, kc = (c & 3) * 8;
      __builtin_amdgcn_global_load_lds(
          (const __attribute__((address_space(1))) void*)(A + (size_t)(bm + row) * K + k0 + kc),
          (__attribute__((address_space(3))) void*)(&As[c * 8]), 16, 0, 0);
      __builtin_amdgcn_global_load_lds(
          (const __attribute__((address_space(1))) void*)(BT + (size_t)(bn + row) * K + k0 + kc),
          (__attribute__((address_space(3))) void*)(&Bs[c * 8]), 16, 0, 0);
    }
    __syncthreads();   // compiler drains vmcnt before s_barrier
    bfx8 af[4], bf[4];
#pragma unroll
    for (int mi = 0; mi < 4; ++mi)
      af[mi] = *(const bfx8*)&As[(wm + mi * 16 + lc) * 32 + lr * 8];
#pragma unroll
    for (int ni = 0; ni < 4; ++ni)
      bf[ni] = *(const bfx8*)&Bs[(wn + ni * 16 + lc) * 32 + lr * 8];
    __builtin_amdgcn_s_setprio(1);
#pragma unroll
    for (int mi = 0; mi < 4; ++mi)
#pragma unroll
      for (int ni = 0; ni < 4; ++ni)
        acc[mi][ni] = __builtin_amdgcn_mfma_f32_16x16x32_bf16(af[mi], bf[ni], acc[mi][ni], 0, 0, 0);
    __builtin_amdgcn_s_setprio(0);
    __syncthreads();
  }
#pragma unroll
  for (int mi = 0; mi < 4; ++mi) {
#pragma unroll
    for (int ni = 0; ni < 4; ++ni) {
      int col = bn + wn + ni * 16 + lc;
      if (col >= Nc) continue;
      float bv = (mode >= 1) ? bias[col] : 0.f;
#pragma unroll
      for (int r = 0; r < 4; ++r) {
        int row = bm + wm + mi * 16 + lr * 4 + r;
        float v = acc[mi][ni][r] + bv;
        if (mode == 2)      v = v / (1.f + __expf(-v));
        else if (mode == 3) v = 1.f / (1.f + __expf(-v));
        if (out_bf) ((unsigned short*)Cout)[(size_t)row * Nc + col] = f2b(v);
        else        ((float*)Cout)[(size_t)row * Nc + col] = v;
      }
    }
  }
}

// ---------------------------------------------------------------- ismod
__global__ __launch_bounds__(256) void ismod_kernel(const int* __restrict__ mp,
                                                    float* __restrict__ ismod) {
  int idx = blockIdx.x * 256 + threadIdx.x;
  int b = idx >> 11, n = idx & 2047;
  const int* p = mp + b * 6;
  bool m = false;
#pragma unroll
  for (int mi = 0; mi < 2; ++mi) {
    int off = p[mi * 3 + 1], len = p[mi * 3 + 2];
    m = m || ((n >= off) && (n < off + len));
  }
  ismod[idx] = m ? 1.f : 0.f;
}

// ---------------------------------------------------------------- layernorm f32->f32
__global__ __launch_bounds__(256) void layernorm_kernel(const float* __restrict__ X,
                                                        float* __restrict__ Y) {
  int r = blockIdx.x;
  const float* xr = X + (size_t)r * DIM_;
  float s = 0.f, ss = 0.f;
  for (int c = threadIdx.x; c < DIM_; c += 256) { float v = xr[c]; s += v; ss += v * v; }
#pragma unroll
  for (int o = 32; o > 0; o >>= 1) { s += __shfl_down(s, o); ss += __shfl_down(ss, o); }
  __shared__ float shs[4], shss[4];
  int w = threadIdx.x >> 6;
  if ((threadIdx.x & 63) == 0) { shs[w] = s; shss[w] = ss; }
  __syncthreads();
  float mu = (shs[0] + shs[1] + shs[2] + shs[3]) * (1.f / DIM_);
  float var = (shss[0] + shss[1] + shss[2] + shss[3]) * (1.f / DIM_) - mu * mu;
  float rstd = rsqrtf(var + 1e-5f);
  for (int c = threadIdx.x; c < DIM_; c += 256)
    Y[(size_t)r * DIM_ + c] = (xr[c] - mu) * rstd;
}

// ---------------------------------------------------------------- modulate
__global__ __launch_bounds__(256) void modulate_kernel(float* __restrict__ H,
                                                       const float* __restrict__ film,
                                                       const float* __restrict__ lng,
                                                       const float* __restrict__ ismod) {
  int idx = blockIdx.x * 256 + threadIdx.x;
  int r = idx >> 10, c = idx & 1023;
  float h = H[idx];
  float g = film[(size_t)r * 2048 + c];
  float bt = film[(size_t)r * 2048 + 1024 + c];
  H[idx] = (ismod[r] != 0.f) ? (h * (g + 1.f) + bt) : (h * (lng[c] + 1.f));
}

// ---------------------------------------------------------------- rmsnorm (Yb bf16 or Yf f32)
__global__ __launch_bounds__(256) void rmsnorm_kernel(const float* __restrict__ X,
                                                      const float* __restrict__ g,
                                                      unsigned short* __restrict__ Yb,
                                                      float* __restrict__ Yf) {
  int r = blockIdx.x;
  const float* xr = X + (size_t)r * DIM_;
  float ss = 0.f;
  for (int c = threadIdx.x; c < DIM_; c += 256) { float v = xr[c]; ss += v * v; }
#pragma unroll
  for (int o = 32; o > 0; o >>= 1) ss += __shfl_down(ss, o);
  __shared__ float shss[4];
  int w = threadIdx.x >> 6;
  if ((threadIdx.x & 63) == 0) shss[w] = ss;
  __syncthreads();
  float tots = shss[0] + shss[1] + shss[2] + shss[3];
  float scale = 32.f / fmaxf(sqrtf(tots), 1e-12f);
  for (int c = threadIdx.x; c < DIM_; c += 256) {
    float v = xr[c] * scale * (g[c] + 1.f);
    if (Yb) Yb[(size_t)r * DIM_ + c] = f2b(v);
    else    Yf[(size_t)r * DIM_ + c] = v;
  }
}

// ---------------------------------------------------------------- rotary on bf16 qkv [ROWS_][3072] (q,k halves), fp32 math
__global__ __launch_bounds__(256) void rotary_kernel(unsigned short* __restrict__ QKV,
                                                     const float* __restrict__ rot) {
  int idx = blockIdx.x * 256 + threadIdx.x;   // ROWS_*1024 pairs
  int r = idx >> 10;
  int c0 = (idx & 1023) * 2;                  // 0..2046
  float f = rot[(r & 2047) * 64 + (c0 & 63)];
  float cs = cosf(f), sn = sinf(f);
  unsigned* p = (unsigned*)(QKV + (size_t)r * 3072 + c0);
  unsigned v = *p;
  float x0 = b2f((unsigned short)(v & 0xFFFF));
  float x1 = b2f((unsigned short)(v >> 16));
  float y0 = x0 * cs - x1 * sn;
  float y1 = x1 * cs + x0 * sn;
  *p = (unsigned)f2b(y0) | ((unsigned)f2b(y1) << 16);
}

// ---------------------------------------------------------------- MFMA flash attention
// block: 256 thr = 4 waves; wave handles 16 q rows. grid (32 qblocks, 32 b*h).
// qb reversed (heavy causal blocks launch first).
__global__ __launch_bounds__(256) void attn_kernel(const unsigned short* __restrict__ QKV,
                                                   const int* __restrict__ mp,
                                                   unsigned short* __restrict__ O) {
  __shared__ unsigned short Ks[64 * KSTR_];     // [key][d]
  __shared__ unsigned short Vt[64 * VSTR_];     // [d][key]
  __shared__ unsigned short Ps[4][16 * PSTR_];  // per-wave P [row][key]
  int bh = blockIdx.y;
  int b = bh >> 4, h = bh & 15;
  int qb = 31 - blockIdx.x;                     // heavy blocks first
  int tid = threadIdx.x, wave = tid >> 6, lane = tid & 63;
  int lg = lane >> 4, ln = lane & 15;
  int off0 = mp[b * 6 + 1], end0 = off0 + mp[b * 6 + 2];
  int off1 = mp[b * 6 + 4], end1 = off1 + mp[b * 6 + 5];
  int qmin = qb * 64;
  int qmax = qmin + 63;

  // Q A-fragments: m = ln -> q row qb*64 + wave*16 + ln
  int qrow = qb * 64 + wave * 16 + ln;
  bfx8 qf0 = *(const bfx8*)(QKV + (size_t)(b * N_ + qrow) * 3072 + h * 64 + lg * 8);
  bfx8 qf1 = *(const bfx8*)(QKV + (size_t)(b * N_ + qrow) * 3072 + h * 64 + 32 + lg * 8);

  fx4 od[4];
#pragma unroll
  for (int i = 0; i < 4; ++i) od[i] = (fx4){0.f, 0.f, 0.f, 0.f};
  float m_[4] = {-3.0e38f, -3.0e38f, -3.0e38f, -3.0e38f};
  float l_[4] = {0.f, 0.f, 0.f, 0.f};
  // output rows owned by this lane: i_[reg] = qb*64 + wave*16 + lg*4 + reg
  int ibase = qb * 64 + wave * 16 + lg * 4;

  for (int jt = 0; jt < 32; ++jt) {
    int j0 = jt * 64;
    if (!((j0 <= qmax) || (qmax >= off0 && j0 < end0) || (qmax >= off1 && j0 < end1))) continue;
    // tile-uniform: is every (i,j) in this tile visible?
    bool full = (j0 + 63 <= qmin) || (qmin >= off0 && j0 + 63 < end0)
             || (qmin >= off1 && j0 + 63 < end1);
    __syncthreads();
    // stage K [key][d]
    for (int e = tid; e < 512; e += 256) {
      int jj = e >> 3, dc = (e & 7) * 8;
      *(bfx8*)&Ks[jj * KSTR_ + dc] =
          *(const bfx8*)(QKV + (size_t)(b * N_ + j0 + jj) * 3072 + 1024 + h * 64 + dc);
    }
    // stage V^T [d][key]
    {
      int key = tid & 63, db = (tid >> 6) * 16;
      const unsigned short* vr = QKV + (size_t)(b * N_ + j0 + key) * 3072 + 2048 + h * 64 + db;
      bfx8 v0 = *(const bfx8*)vr;
      bfx8 v1 = *(const bfx8*)(vr + 8);
#pragma unroll
      for (int t = 0; t < 8; ++t) {
        Vt[(db + t) * VSTR_ + key]     = (unsigned short)v0[t];
        Vt[(db + 8 + t) * VSTR_ + key] = (unsigned short)v1[t];
      }
    }
    __syncthreads();
    // QK^T: S[16 q][64 key]
    fx4 sf[4];
    __builtin_amdgcn_s_setprio(1);
#pragma unroll
    for (int kn = 0; kn < 4; ++kn) {
      fx4 a = (fx4){0.f, 0.f, 0.f, 0.f};
      bfx8 b0 = *(const bfx8*)&Ks[(kn * 16 + ln) * KSTR_ + lg * 8];
      bfx8 b1 = *(const bfx8*)&Ks[(kn * 16 + ln) * KSTR_ + 32 + lg * 8];
      a = __builtin_amdgcn_mfma_f32_16x16x32_bf16(qf0, b0, a, 0, 0, 0);
      a = __builtin_amdgcn_mfma_f32_16x16x32_bf16(qf1, b1, a, 0, 0, 0);
      sf[kn] = a;
    }
    __builtin_amdgcn_s_setprio(0);
    // softcap: sim = raw*0.125; t = 50*tanh(sim/50) = 50 - 100/(exp(sim/25)+1)
    // raw*0.125/25 = raw*0.005. exp->inf is safe (100/inf = 0 -> t = 50).
    float sv[4][4];
#pragma unroll
    for (int kn = 0; kn < 4; ++kn)
#pragma unroll
      for (int reg = 0; reg < 4; ++reg) {
        float e2 = __expf(sf[kn][reg] * 0.005f);
        float r = __builtin_amdgcn_rcpf(e2 + 1.f);
        sv[kn][reg] = fmaf(-100.f, r, 50.f);
      }
    if (!full) {   // uniform branch: only diagonal/span-boundary tiles pay the mask
#pragma unroll
      for (int kn = 0; kn < 4; ++kn) {
        int j = j0 + kn * 16 + ln;
#pragma unroll
        for (int reg = 0; reg < 4; ++reg) {
          int i = ibase + reg;
          bool ok = (i >= j) || (i >= off0 && j < end0) || (i >= off1 && j < end1);
          sv[kn][reg] = ok ? sv[kn][reg] : -1.0e30f;
        }
      }
    }
    // online softmax per row: butterfly over the 16 lanes sharing each row
    float tm[4];
#pragma unroll
    for (int reg = 0; reg < 4; ++reg)
      tm[reg] = fmaxf(fmaxf(sv[0][reg], sv[1][reg]), fmaxf(sv[2][reg], sv[3][reg]));
#pragma unroll
    for (int x = 1; x < 16; x <<= 1)
#pragma unroll
      for (int reg = 0; reg < 4; ++reg) tm[reg] = fmaxf(tm[reg], __shfl_xor(tm[reg], x));
    float scl[4];
#pragma unroll
    for (int reg = 0; reg < 4; ++reg) {
      float mn = fmaxf(m_[reg], tm[reg]);
      scl[reg] = __expf(m_[reg] - mn);
      m_[reg] = mn;
    }
    float ts[4] = {0.f, 0.f, 0.f, 0.f};
#pragma unroll
    for (int kn = 0; kn < 4; ++kn)
#pragma unroll
      for (int reg = 0; reg < 4; ++reg) {
        float pp = __expf(sv[kn][reg] - m_[reg]);
        sv[kn][reg] = pp;
        ts[reg] += pp;
      }
#pragma unroll
    for (int x = 1; x < 16; x <<= 1)
#pragma unroll
      for (int reg = 0; reg < 4; ++reg) ts[reg] += __shfl_xor(ts[reg], x);
#pragma unroll
    for (int reg = 0; reg < 4; ++reg) l_[reg] = l_[reg] * scl[reg] + ts[reg];
    // P -> LDS (C-layout scatter), re-read as A-fragments
#pragma unroll
    for (int kn = 0; kn < 4; ++kn)
#pragma unroll
      for (int reg = 0; reg < 4; ++reg)
        Ps[wave][(lg * 4 + reg) * PSTR_ + kn * 16 + ln] = f2b(sv[kn][reg]);
    // rescale O
#pragma unroll
    for (int dn = 0; dn < 4; ++dn)
#pragma unroll
      for (int reg = 0; reg < 4; ++reg) od[dn][reg] *= scl[reg];
    bfx8 pf0 = *(const bfx8*)&Ps[wave][ln * PSTR_ + lg * 8];
    bfx8 pf1 = *(const bfx8*)&Ps[wave][ln * PSTR_ + 32 + lg * 8];
    __builtin_amdgcn_s_setprio(1);
#pragma unroll
    for (int dn = 0; dn < 4; ++dn) {
      bfx8 v0 = *(const bfx8*)&Vt[(dn * 16 + ln) * VSTR_ + lg * 8];
      bfx8 v1 = *(const bfx8*)&Vt[(dn * 16 + ln) * VSTR_ + 32 + lg * 8];
      od[dn] = __builtin_amdgcn_mfma_f32_16x16x32_bf16(pf0, v0, od[dn], 0, 0, 0);
      od[dn] = __builtin_amdgcn_mfma_f32_16x16x32_bf16(pf1, v1, od[dn], 0, 0, 0);
    }
    __builtin_amdgcn_s_setprio(0);
  }
  // write O rows: (row = ibase+reg, col = h*64 + dn*16+ln)
#pragma unroll
  for (int reg = 0; reg < 4; ++reg) {
    float inv = 1.f / l_[reg];
    unsigned short* orow = O + (size_t)(b * N_ + ibase + reg) * 1024 + h * 64;
#pragma unroll
    for (int dn = 0; dn < 4; ++dn)
      orow[dn * 16 + ln] = f2b(od[dn][reg] * inv);
  }
}

// ---------------------------------------------------------------- geglu: ff1 chunk f32 [1024][5460] -> mid bf16 (stride 2752)
__global__ __launch_bounds__(256) void geglu_kernel(const float* __restrict__ FF1,
                                                    unsigned short* __restrict__ MID) {
  int c = blockIdx.x * 256 + threadIdx.x;
  int r = blockIdx.y;
  if (c >= KM_) return;
  unsigned short outv = 0;
  if (c < DFF_) {
    float u = FF1[(size_t)r * DFF1_ + c];
    float g = FF1[(size_t)r * DFF1_ + DFF_ + c];
    float ge = 0.5f * g * (1.f + erff(g * 0.70710678118654752440f));
    outv = f2b(ge * u);
  }
  MID[(size_t)r * KM_ + c] = outv;
}

// ---------------------------------------------------------------- residual
__global__ __launch_bounds__(256) void residual_kernel(float* __restrict__ X,
                                                       const float* __restrict__ outb,
                                                       const float* __restrict__ gate,
                                                       const float* __restrict__ ls,
                                                       const float* __restrict__ ismod) {
  int idx = blockIdx.x * 256 + threadIdx.x;
  int r = idx >> 10, c = idx & 1023;
  float ov = outb[idx];
  float v = (ismod[r] != 0.f) ? (ov * gate[idx]) : (ov * (ls[c] + 1.f));
  X[idx] += v;
}

// ================================================================ launch
extern "C" void kernel_launch(void* const* d_in, const int* in_sizes, int n_in,
                              void* d_out, int out_size, void* d_ws, size_t ws_size,
                              hipStream_t stream) {
  const float* in_x   = (const float*)d_in[0];
  const float* times  = (const float*)d_in[1];
  const float* rotary = (const float*)d_in[2];
  const float* fwgt   = (const float*)d_in[3];
  const float* time_w = (const float*)d_in[4];
  const float* time_b = (const float*)d_in[5];
  const float* afw    = (const float*)d_in[6];
  const float* afb    = (const float*)d_in[7];
  const float* azw    = (const float*)d_in[8];
  const float* azb    = (const float*)d_in[9];
  const float* alng   = (const float*)d_in[10];
  const float* als    = (const float*)d_in[11];
  const float* armsg  = (const float*)d_in[12];
  const float* wqkv   = (const float*)d_in[13];
  const float* wout   = (const float*)d_in[14];
  const float* ffw    = (const float*)d_in[15];
  const float* ffb    = (const float*)d_in[16];
  const float* fzw    = (const float*)d_in[17];
  const float* fzb    = (const float*)d_in[18];
  const float* flng   = (const float*)d_in[19];
  const float* fls    = (const float*)d_in[20];
  const float* frmsg  = (const float*)d_in[21];
  const float* fw1    = (const float*)d_in[22];
  const float* fb1    = (const float*)d_in[23];
  const float* fw2    = (const float*)d_in[24];
  const float* fb2    = (const float*)d_in[25];
  const float* fing   = (const float*)d_in[26];
  const int*   mp     = (const int*)d_in[27];
  float* out = (float*)d_out;

  char* p = (char*)d_ws;
  unsigned short* wT   = (unsigned short*)p;      p += 17301504;
  float* f_x           = (float*)p;               p += 16777216;
  float* f_ln          = (float*)p;               p += 16777216;
  float* f_o           = (float*)p;               p += 16777216;
  unsigned short* cond = (unsigned short*)p;      p += 33554432;  // [4096][4096] bf16
  unsigned short* hbf  = (unsigned short*)p;      p += 8388608;   // [4096][1024] bf16
  float* film          = (float*)p;               p += 33554432;  // [4096][2048] f32
  float* gate          = (float*)p;               p += 16777216;  // [4096][1024] f32
  char* arena          = p;                       p += 58720256;
  float* f_ismod       = (float*)p;               p += 16384;

  unsigned short* qkv    = (unsigned short*)arena;              // [4096][3072] bf16 (25.2 MB)
  unsigned short* attno  = (unsigned short*)(arena + 50331648); // [4096][1024] bf16 (8.4 MB)
  float* ff1c            = (float*)arena;                       // [1024][5460] f32 chunk (22.4 MB)
  unsigned short* mid    = (unsigned short*)(arena + 22364160); // [4096][2752] bf16 (22.5 MB)
  unsigned short* four   = (unsigned short*)arena;              // [4096][1056] bf16

  auto gemm = [&](const unsigned short* A, const float* bias, void* C,
                  int K, int Nc, int mode, int out_bf, int mtiles) {
    mfma_gemm<<<dim3((Nc + 127) / 128, mtiles), 256, 0, stream>>>(A, wT, bias, C, K, Nc, mode, out_bf);
  };
  auto transp = [&](const float* W, int K, int N, int KP) {
    transpose_w<<<dim3(KP / 32, (N + 31) / 32), dim3(32, 8), 0, stream>>>(W, wT, K, N, KP);
  };

  // ---- conditioning ----
  fourier_kernel<<<ROWS_, 256, 0, stream>>>(times, fwgt, four);
  transp(time_w, 1025, DCOND_, KF_);
  gemm(four, time_b, cond, KF_, DCOND_, 2, 1, 32);
  ismod_kernel<<<ROWS_ / 256, 256, 0, stream>>>(mp, f_ismod);
  hipMemcpyAsync(f_x, in_x, (size_t)ROWS_ * DIM_ * sizeof(float),
                 hipMemcpyDeviceToDevice, stream);

  for (int l = 0; l < 2; ++l) {
    // ---- attention block ----
    layernorm_kernel<<<ROWS_, 256, 0, stream>>>(f_x, f_ln);
    transp(afw + (size_t)l * DCOND_ * 2048, DCOND_, 2048, DCOND_);
    gemm(cond, afb + l * 2048, film, DCOND_, 2048, 1, 0, 32);
    modulate_kernel<<<(ROWS_ * DIM_) / 256, 256, 0, stream>>>(f_ln, film, alng + l * 1024, f_ismod);
    rmsnorm_kernel<<<ROWS_, 256, 0, stream>>>(f_ln, armsg + l * 1024, hbf, nullptr);
    transp(wqkv + (size_t)l * 1024 * 3072, 1024, 3072, 1024);
    gemm(hbf, nullptr, qkv, 1024, 3072, 0, 1, 32);
    rotary_kernel<<<(ROWS_ * 1024) / 256, 256, 0, stream>>>(qkv, rotary);
    attn_kernel<<<dim3(32, 32), 256, 0, stream>>>(qkv, mp, attno);
    transp(wout + (size_t)l * 1024 * 1024, 1024, 1024, 1024);
    gemm(attno, nullptr, f_o, 1024, 1024, 0, 0, 32);
    transp(azw + (size_t)l * DCOND_ * 1024, DCOND_, 1024, DCOND_);
    gemm(cond, azb + l * 1024, gate, DCOND_, 1024, 3, 0, 32);
    residual_kernel<<<(ROWS_ * DIM_) / 256, 256, 0, stream>>>(f_x, f_o, gate, als + l * 1024, f_ismod);

    // ---- feed-forward block ----
    layernorm_kernel<<<ROWS_, 256, 0, stream>>>(f_x, f_ln);
    transp(ffw + (size_t)l * DCOND_ * 2048, DCOND_, 2048, DCOND_);
    gemm(cond, ffb + l * 2048, film, DCOND_, 2048, 1, 0, 32);
    modulate_kernel<<<(ROWS_ * DIM_) / 256, 256, 0, stream>>>(f_ln, film, flng + l * 1024, f_ismod);
    rmsnorm_kernel<<<ROWS_, 256, 0, stream>>>(f_ln, frmsg + l * 1024, hbf, nullptr);
    transp(fw1 + (size_t)l * 1024 * DFF1_, 1024, DFF1_, 1024);
    for (int rc = 0; rc < 4; ++rc) {
      gemm(hbf + (size_t)rc * 1024 * 1024, fb1 + l * DFF1_, ff1c, 1024, DFF1_, 1, 0, 8);
      geglu_kernel<<<dim3((KM_ + 255) / 256, 1024), 256, 0, stream>>>(
          ff1c, mid + (size_t)rc * 1024 * KM_);
    }
    transp(fw2 + (size_t)l * DFF_ * 1024, DFF_, 1024, KM_);
    gemm(mid, fb2 + l * 1024, f_o, KM_, 1024, 1, 0, 32);
    transp(fzw + (size_t)l * DCOND_ * 1024, DCOND_, 1024, DCOND_);
    gemm(cond, fzb + l * 1024, gate, DCOND_, 1024, 3, 0, 32);
    residual_kernel<<<(ROWS_ * DIM_) / 256, 256, 0, stream>>>(f_x, f_o, gate, fls + l * 1024, f_ismod);
  }

  // final rmsnorm -> fp32 out
  rmsnorm_kernel<<<ROWS_, 256, 0, stream>>>(f_x, fing, nullptr, out);
}

// Round 3
// 2054.865 us; speedup vs baseline: 1.2790x; 1.1479x over previous
//
#include <hip/hip_runtime.h>
#include <math.h>

#define B_      2
#define N_      2048
#define DIM_    1024
#define ROWS_   4096      // B*N
#define DCOND_  4096
#define DFF_    2730
#define DFF1_   5460
#define KF_     1056      // fourier K padded (1025 -> 1056)
#define KM_     2752      // geglu-mid K padded (2730 -> 2752)
#define SCALE_  0.125f
#define TWO_PI_ 6.28318530717958647692f

#define KSTR_   72        // K-tile LDS row stride (shorts)
#define VSTR_   72        // V^T-tile LDS row stride
#define PSTR_   68        // P-tile LDS row stride

typedef __attribute__((ext_vector_type(8))) short bfx8;   // 8 bf16 = 4 VGPR
typedef __attribute__((ext_vector_type(4))) float fx4;    // MFMA accum

__device__ __forceinline__ float b2f(unsigned short u) {
  return __uint_as_float(((unsigned)u) << 16);
}
__device__ __forceinline__ unsigned short f2b(float f) {  // RNE
  unsigned x = __float_as_uint(f);
  return (unsigned short)((x + 0x7FFF + ((x >> 16) & 1)) >> 16);
}

// DPP row-rotate (16-lane row) — pure-VALU cross-lane, replaces ds_swizzle shuffles
template <int CTRL>
__device__ __forceinline__ float dppf(float v) {
  return __uint_as_float((unsigned)__builtin_amdgcn_update_dpp(
      0, (int)__float_as_uint(v), CTRL, 0xf, 0xf, true));
}
__device__ __forceinline__ float rowmax16(float v) {
  v = fmaxf(v, dppf<0x121>(v));   // row_ror:1
  v = fmaxf(v, dppf<0x122>(v));   // row_ror:2
  v = fmaxf(v, dppf<0x124>(v));   // row_ror:4
  v = fmaxf(v, dppf<0x128>(v));   // row_ror:8
  return v;
}
__device__ __forceinline__ float rowsum16(float v) {
  v += dppf<0x121>(v);
  v += dppf<0x122>(v);
  v += dppf<0x124>(v);
  v += dppf<0x128>(v);
  return v;
}

// ---------------------------------------------------------------- fourier -> bf16 [4096][1056], zero-padded
__global__ __launch_bounds__(256) void fourier_kernel(const float* __restrict__ times,
                                                      const float* __restrict__ fw,
                                                      unsigned short* __restrict__ F) {
  int r = blockIdx.x;
  float tv = times[r];
  unsigned short* Fr = F + (size_t)r * KF_;
  for (int c = threadIdx.x; c < KF_; c += 256) {
    float v;
    if (c == 0)          v = tv;
    else if (c <= 512)   v = sinf(tv * fw[c - 1] * TWO_PI_);
    else if (c <= 1024)  v = cosf(tv * fw[c - 513] * TWO_PI_);
    else                 v = 0.f;
    Fr[c] = f2b(v);
  }
}

// ---------------------------------------------------------------- weight transpose: W f32 [K][N] -> WT bf16 [N][KP]
__global__ __launch_bounds__(256) void transpose_w(const float* __restrict__ W,
                                                   unsigned short* __restrict__ WT,
                                                   int K, int N, int KP) {
  __shared__ float t[32][33];
  int tx = threadIdx.x, ty = threadIdx.y;    // 32 x 8
  int k0 = blockIdx.x * 32, n0 = blockIdx.y * 32;
#pragma unroll
  for (int i = 0; i < 4; ++i) {
    int k = k0 + ty + i * 8, n = n0 + tx;
    t[ty + i * 8][tx] = (k < K && n < N) ? W[(size_t)k * N + n] : 0.f;
  }
  __syncthreads();
#pragma unroll
  for (int i = 0; i < 4; ++i) {
    int n = n0 + ty + i * 8;
    if (n < N) WT[(size_t)n * KP + k0 + tx] = f2b(t[tx][ty + i * 8]);
  }
}

// ---------------------------------------------------------------- V transpose: qkv v-part -> VT[bh][64 d][2048 n] bf16
__global__ __launch_bounds__(256) void vtrans_kernel(const unsigned short* __restrict__ QKV,
                                                     unsigned short* __restrict__ VT) {
  __shared__ unsigned short t[32][33];
  int bh = blockIdx.z;                      // 0..31
  int b = bh >> 4, h = bh & 15;
  int n0 = blockIdx.x * 32, d0 = blockIdx.y * 32;
  int tx = threadIdx.x, ty = threadIdx.y;   // 32 x 8
#pragma unroll
  for (int i = 0; i < 4; ++i) {
    int n = n0 + ty + i * 8;
    t[ty + i * 8][tx] = QKV[(size_t)(b * N_ + n) * 3072 + 2048 + h * 64 + d0 + tx];
  }
  __syncthreads();
#pragma unroll
  for (int i = 0; i < 4; ++i) {
    int d = d0 + ty + i * 8;
    VT[((size_t)bh * 64 + d) * N_ + n0 + tx] = t[tx][ty + i * 8];
  }
}

// ---------------------------------------------------------------- MFMA GEMM (global_load_lds width-16 staging, m97 structure)
// mode: 0 none, 1 bias, 2 bias+silu, 3 bias+sigmoid,
//       4 fused film+gate: col<2048 -> bias+linear -> (float*)Cout  [stride 2048]
//                          col>=2048 -> bias2+sigmoid -> (float*)Cout2 [stride 1024]
__global__ __launch_bounds__(256) void mfma_gemm(const unsigned short* __restrict__ A,
                                                 const unsigned short* __restrict__ BT,
                                                 const float* __restrict__ bias,
                                                 const float* __restrict__ bias2,
                                                 void* __restrict__ Cout,
                                                 void* __restrict__ Cout2,
                                                 int K, int Nc, int mode, int out_bf) {
  __shared__ unsigned short As[128 * 32];
  __shared__ unsigned short Bs[128 * 32];
  int tid = threadIdx.x;
  int wave = tid >> 6, lane = tid & 63;
  int bm = blockIdx.y * 128, bn = blockIdx.x * 128;
  int wm = (wave >> 1) * 64, wn = (wave & 1) * 64;
  int lr = lane >> 4, lc = lane & 15;
  fx4 acc[4][4];
#pragma unroll
  for (int i = 0; i < 4; ++i)
#pragma unroll
    for (int j = 0; j < 4; ++j) acc[i][j] = (fx4){0.f, 0.f, 0.f, 0.f};

  for (int k0 = 0; k0 < K; k0 += 32) {
#pragma unroll
    for (int i = 0; i < 2; ++i) {
      int c = tid + i * 256;
      int row = c >> 2, kc = (c & 3) * 8;
      __builtin_amdgcn_global_load_lds(
          (const __attribute__((address_space(1))) void*)(A + (size_t)(bm + row) * K + k0 + kc),
          (__attribute__((address_space(3))) void*)(&As[c * 8]), 16, 0, 0);
      __builtin_amdgcn_global_load_lds(
          (const __attribute__((address_space(1))) void*)(BT + (size_t)(bn + row) * K + k0 + kc),
          (__attribute__((address_space(3))) void*)(&Bs[c * 8]), 16, 0, 0);
    }
    __syncthreads();
    bfx8 af[4], bf[4];
#pragma unroll
    for (int mi = 0; mi < 4; ++mi)
      af[mi] = *(const bfx8*)&As[(wm + mi * 16 + lc) * 32 + lr * 8];
#pragma unroll
    for (int ni = 0; ni < 4; ++ni)
      bf[ni] = *(const bfx8*)&Bs[(wn + ni * 16 + lc) * 32 + lr * 8];
    __builtin_amdgcn_s_setprio(1);
#pragma unroll
    for (int mi = 0; mi < 4; ++mi)
#pragma unroll
      for (int ni = 0; ni < 4; ++ni)
        acc[mi][ni] = __builtin_amdgcn_mfma_f32_16x16x32_bf16(af[mi], bf[ni], acc[mi][ni], 0, 0, 0);
    __builtin_amdgcn_s_setprio(0);
    __syncthreads();
  }
#pragma unroll
  for (int mi = 0; mi < 4; ++mi) {
#pragma unroll
    for (int ni = 0; ni < 4; ++ni) {
      int col = bn + wn + ni * 16 + lc;
      if (col >= Nc) continue;
      if (mode == 4) {
        if (col < 2048) {
          float bv = bias[col];
#pragma unroll
          for (int r = 0; r < 4; ++r) {
            int row = bm + wm + mi * 16 + lr * 4 + r;
            ((float*)Cout)[(size_t)row * 2048 + col] = acc[mi][ni][r] + bv;
          }
        } else {
          int c2 = col - 2048;
          float bv = bias2[c2];
#pragma unroll
          for (int r = 0; r < 4; ++r) {
            int row = bm + wm + mi * 16 + lr * 4 + r;
            float v = acc[mi][ni][r] + bv;
            ((float*)Cout2)[(size_t)row * 1024 + c2] = 1.f / (1.f + __expf(-v));
          }
        }
        continue;
      }
      float bv = (mode >= 1) ? bias[col] : 0.f;
#pragma unroll
      for (int r = 0; r < 4; ++r) {
        int row = bm + wm + mi * 16 + lr * 4 + r;
        float v = acc[mi][ni][r] + bv;
        if (mode == 2)      v = v / (1.f + __expf(-v));
        else if (mode == 3) v = 1.f / (1.f + __expf(-v));
        if (out_bf) ((unsigned short*)Cout)[(size_t)row * Nc + col] = f2b(v);
        else        ((float*)Cout)[(size_t)row * Nc + col] = v;
      }
    }
  }
}

// ---------------------------------------------------------------- ismod
__global__ __launch_bounds__(256) void ismod_kernel(const int* __restrict__ mp,
                                                    float* __restrict__ ismod) {
  int idx = blockIdx.x * 256 + threadIdx.x;
  int b = idx >> 11, n = idx & 2047;
  const int* p = mp + b * 6;
  bool m = false;
#pragma unroll
  for (int mi = 0; mi < 2; ++mi) {
    int off = p[mi * 3 + 1], len = p[mi * 3 + 2];
    m = m || ((n >= off) && (n < off + len));
  }
  ismod[idx] = m ? 1.f : 0.f;
}

// ---------------------------------------------------------------- layernorm f32->f32
__global__ __launch_bounds__(256) void layernorm_kernel(const float* __restrict__ X,
                                                        float* __restrict__ Y) {
  int r = blockIdx.x;
  const float* xr = X + (size_t)r * DIM_;
  float s = 0.f, ss = 0.f;
  for (int c = threadIdx.x; c < DIM_; c += 256) { float v = xr[c]; s += v; ss += v * v; }
#pragma unroll
  for (int o = 32; o > 0; o >>= 1) { s += __shfl_down(s, o); ss += __shfl_down(ss, o); }
  __shared__ float shs[4], shss[4];
  int w = threadIdx.x >> 6;
  if ((threadIdx.x & 63) == 0) { shs[w] = s; shss[w] = ss; }
  __syncthreads();
  float mu = (shs[0] + shs[1] + shs[2] + shs[3]) * (1.f / DIM_);
  float var = (shss[0] + shss[1] + shss[2] + shss[3]) * (1.f / DIM_) - mu * mu;
  float rstd = rsqrtf(var + 1e-5f);
  for (int c = threadIdx.x; c < DIM_; c += 256)
    Y[(size_t)r * DIM_ + c] = (xr[c] - mu) * rstd;
}

// ---------------------------------------------------------------- modulate
__global__ __launch_bounds__(256) void modulate_kernel(float* __restrict__ H,
                                                       const float* __restrict__ film,
                                                       const float* __restrict__ lng,
                                                       const float* __restrict__ ismod) {
  int idx = blockIdx.x * 256 + threadIdx.x;
  int r = idx >> 10, c = idx & 1023;
  float h = H[idx];
  float g = film[(size_t)r * 2048 + c];
  float bt = film[(size_t)r * 2048 + 1024 + c];
  H[idx] = (ismod[r] != 0.f) ? (h * (g + 1.f) + bt) : (h * (lng[c] + 1.f));
}

// ---------------------------------------------------------------- rmsnorm (Yb bf16 or Yf f32)
__global__ __launch_bounds__(256) void rmsnorm_kernel(const float* __restrict__ X,
                                                      const float* __restrict__ g,
                                                      unsigned short* __restrict__ Yb,
                                                      float* __restrict__ Yf) {
  int r = blockIdx.x;
  const float* xr = X + (size_t)r * DIM_;
  float ss = 0.f;
  for (int c = threadIdx.x; c < DIM_; c += 256) { float v = xr[c]; ss += v * v; }
#pragma unroll
  for (int o = 32; o > 0; o >>= 1) ss += __shfl_down(ss, o);
  __shared__ float shss[4];
  int w = threadIdx.x >> 6;
  if ((threadIdx.x & 63) == 0) shss[w] = ss;
  __syncthreads();
  float tots = shss[0] + shss[1] + shss[2] + shss[3];
  float scale = 32.f / fmaxf(sqrtf(tots), 1e-12f);
  for (int c = threadIdx.x; c < DIM_; c += 256) {
    float v = xr[c] * scale * (g[c] + 1.f);
    if (Yb) Yb[(size_t)r * DIM_ + c] = f2b(v);
    else    Yf[(size_t)r * DIM_ + c] = v;
  }
}

// ---------------------------------------------------------------- rotary on bf16 qkv [ROWS_][3072] (q,k halves), fp32 math
__global__ __launch_bounds__(256) void rotary_kernel(unsigned short* __restrict__ QKV,
                                                     const float* __restrict__ rot) {
  int idx = blockIdx.x * 256 + threadIdx.x;   // ROWS_*1024 pairs
  int r = idx >> 10;
  int c0 = (idx & 1023) * 2;                  // 0..2046
  float f = rot[(r & 2047) * 64 + (c0 & 63)];
  float cs = cosf(f), sn = sinf(f);
  unsigned* p = (unsigned*)(QKV + (size_t)r * 3072 + c0);
  unsigned v = *p;
  float x0 = b2f((unsigned short)(v & 0xFFFF));
  float x1 = b2f((unsigned short)(v >> 16));
  float y0 = x0 * cs - x1 * sn;
  float y1 = x1 * cs + x0 * sn;
  *p = (unsigned)f2b(y0) | ((unsigned)f2b(y1) << 16);
}

// ---------------------------------------------------------------- MFMA flash attention
// block: 256 thr = 4 waves; wave handles 16 q rows. grid (32 qblocks, 32 b*h).
// qb reversed (heavy causal blocks launch first). V pre-transposed globally.
__global__ __launch_bounds__(256) void attn_kernel(const unsigned short* __restrict__ QKV,
                                                   const unsigned short* __restrict__ VTg,
                                                   const int* __restrict__ mp,
                                                   unsigned short* __restrict__ O) {
  __shared__ unsigned short Ks[64 * KSTR_];     // [key][d]
  __shared__ unsigned short Vt[64 * VSTR_];     // [d][key]
  __shared__ unsigned short Ps[4][16 * PSTR_];  // per-wave P [row][key]
  int bh = blockIdx.y;
  int b = bh >> 4, h = bh & 15;
  int qb = 31 - blockIdx.x;                     // heavy blocks first
  int tid = threadIdx.x, wave = tid >> 6, lane = tid & 63;
  int lg = lane >> 4, ln = lane & 15;
  int off0 = mp[b * 6 + 1], end0 = off0 + mp[b * 6 + 2];
  int off1 = mp[b * 6 + 4], end1 = off1 + mp[b * 6 + 5];
  int qmin = qb * 64;
  int qmax = qmin + 63;

  // Q A-fragments: m = ln -> q row qb*64 + wave*16 + ln
  int qrow = qb * 64 + wave * 16 + ln;
  bfx8 qf0 = *(const bfx8*)(QKV + (size_t)(b * N_ + qrow) * 3072 + h * 64 + lg * 8);
  bfx8 qf1 = *(const bfx8*)(QKV + (size_t)(b * N_ + qrow) * 3072 + h * 64 + 32 + lg * 8);

  fx4 od[4];
#pragma unroll
  for (int i = 0; i < 4; ++i) od[i] = (fx4){0.f, 0.f, 0.f, 0.f};
  float m_[4] = {-3.0e38f, -3.0e38f, -3.0e38f, -3.0e38f};
  float l_[4] = {0.f, 0.f, 0.f, 0.f};
  int ibase = qb * 64 + wave * 16 + lg * 4;

  for (int jt = 0; jt < 32; ++jt) {
    int j0 = jt * 64;
    if (!((j0 <= qmax) || (qmax >= off0 && j0 < end0) || (qmax >= off1 && j0 < end1))) continue;
    bool full = (j0 + 63 <= qmin) || (qmin >= off0 && j0 + 63 < end0)
             || (qmin >= off1 && j0 + 63 < end1);
    __syncthreads();
    // stage K [key][d]
    for (int e = tid; e < 512; e += 256) {
      int jj = e >> 3, dc = (e & 7) * 8;
      *(bfx8*)&Ks[jj * KSTR_ + dc] =
          *(const bfx8*)(QKV + (size_t)(b * N_ + j0 + jj) * 3072 + 1024 + h * 64 + dc);
    }
    // stage V^T [d][key] — coalesced from pre-transposed global (no scalar scatter)
    for (int e = tid; e < 512; e += 256) {
      int d = e >> 3, kc = (e & 7) * 8;
      *(bfx8*)&Vt[d * VSTR_ + kc] =
          *(const bfx8*)(VTg + ((size_t)bh * 64 + d) * N_ + j0 + kc);
    }
    __syncthreads();
    // QK^T: S[16 q][64 key]
    fx4 sf[4];
    __builtin_amdgcn_s_setprio(1);
#pragma unroll
    for (int kn = 0; kn < 4; ++kn) {
      fx4 a = (fx4){0.f, 0.f, 0.f, 0.f};
      bfx8 b0 = *(const bfx8*)&Ks[(kn * 16 + ln) * KSTR_ + lg * 8];
      bfx8 b1 = *(const bfx8*)&Ks[(kn * 16 + ln) * KSTR_ + 32 + lg * 8];
      a = __builtin_amdgcn_mfma_f32_16x16x32_bf16(qf0, b0, a, 0, 0, 0);
      a = __builtin_amdgcn_mfma_f32_16x16x32_bf16(qf1, b1, a, 0, 0, 0);
      sf[kn] = a;
    }
    __builtin_amdgcn_s_setprio(0);
    // softcap: t = 50*tanh(sim/50) = 50 - 100/(exp(sim/25)+1); sim = raw*0.125
    float sv[4][4];
#pragma unroll
    for (int kn = 0; kn < 4; ++kn)
#pragma unroll
      for (int reg = 0; reg < 4; ++reg) {
        float e2 = __expf(sf[kn][reg] * 0.005f);
        float r = __builtin_amdgcn_rcpf(e2 + 1.f);
        sv[kn][reg] = fmaf(-100.f, r, 50.f);
      }
    if (!full) {
#pragma unroll
      for (int kn = 0; kn < 4; ++kn) {
        int j = j0 + kn * 16 + ln;
#pragma unroll
        for (int reg = 0; reg < 4; ++reg) {
          int i = ibase + reg;
          bool ok = (i >= j) || (i >= off0 && j < end0) || (i >= off1 && j < end1);
          sv[kn][reg] = ok ? sv[kn][reg] : -1.0e30f;
        }
      }
    }
    // online softmax per row: DPP row-rotate reduction across the 16 lanes/row
    float scl[4];
#pragma unroll
    for (int reg = 0; reg < 4; ++reg) {
      float tm = fmaxf(fmaxf(sv[0][reg], sv[1][reg]), fmaxf(sv[2][reg], sv[3][reg]));
      tm = rowmax16(tm);
      float mn = fmaxf(m_[reg], tm);
      scl[reg] = __expf(m_[reg] - mn);
      m_[reg] = mn;
    }
    float ts[4];
#pragma unroll
    for (int reg = 0; reg < 4; ++reg) {
      float t = 0.f;
#pragma unroll
      for (int kn = 0; kn < 4; ++kn) {
        float pp = __expf(sv[kn][reg] - m_[reg]);
        sv[kn][reg] = pp;
        t += pp;
      }
      ts[reg] = rowsum16(t);
    }
#pragma unroll
    for (int reg = 0; reg < 4; ++reg) l_[reg] = l_[reg] * scl[reg] + ts[reg];
    // P -> LDS (C-layout scatter), re-read as A-fragments
#pragma unroll
    for (int kn = 0; kn < 4; ++kn)
#pragma unroll
      for (int reg = 0; reg < 4; ++reg)
        Ps[wave][(lg * 4 + reg) * PSTR_ + kn * 16 + ln] = f2b(sv[kn][reg]);
    // rescale O
#pragma unroll
    for (int dn = 0; dn < 4; ++dn)
#pragma unroll
      for (int reg = 0; reg < 4; ++reg) od[dn][reg] *= scl[reg];
    bfx8 pf0 = *(const bfx8*)&Ps[wave][ln * PSTR_ + lg * 8];
    bfx8 pf1 = *(const bfx8*)&Ps[wave][ln * PSTR_ + 32 + lg * 8];
    __builtin_amdgcn_s_setprio(1);
#pragma unroll
    for (int dn = 0; dn < 4; ++dn) {
      bfx8 v0 = *(const bfx8*)&Vt[(dn * 16 + ln) * VSTR_ + lg * 8];
      bfx8 v1 = *(const bfx8*)&Vt[(dn * 16 + ln) * VSTR_ + 32 + lg * 8];
      od[dn] = __builtin_amdgcn_mfma_f32_16x16x32_bf16(pf0, v0, od[dn], 0, 0, 0);
      od[dn] = __builtin_amdgcn_mfma_f32_16x16x32_bf16(pf1, v1, od[dn], 0, 0, 0);
    }
    __builtin_amdgcn_s_setprio(0);
  }
#pragma unroll
  for (int reg = 0; reg < 4; ++reg) {
    float inv = 1.f / l_[reg];
    unsigned short* orow = O + (size_t)(b * N_ + ibase + reg) * 1024 + h * 64;
#pragma unroll
    for (int dn = 0; dn < 4; ++dn)
      orow[dn * 16 + ln] = f2b(od[dn][reg] * inv);
  }
}

// ---------------------------------------------------------------- geglu: ff1 chunk f32 [1024][5460] -> mid bf16 (stride 2752)
__global__ __launch_bounds__(256) void geglu_kernel(const float* __restrict__ FF1,
                                                    unsigned short* __restrict__ MID) {
  int c = blockIdx.x * 256 + threadIdx.x;
  int r = blockIdx.y;
  if (c >= KM_) return;
  unsigned short outv = 0;
  if (c < DFF_) {
    float u = FF1[(size_t)r * DFF1_ + c];
    float g = FF1[(size_t)r * DFF1_ + DFF_ + c];
    float ge = 0.5f * g * (1.f + erff(g * 0.70710678118654752440f));
    outv = f2b(ge * u);
  }
  MID[(size_t)r * KM_ + c] = outv;
}

// ---------------------------------------------------------------- residual
__global__ __launch_bounds__(256) void residual_kernel(float* __restrict__ X,
                                                       const float* __restrict__ outb,
                                                       const float* __restrict__ gate,
                                                       const float* __restrict__ ls,
                                                       const float* __restrict__ ismod) {
  int idx = blockIdx.x * 256 + threadIdx.x;
  int r = idx >> 10, c = idx & 1023;
  float ov = outb[idx];
  float v = (ismod[r] != 0.f) ? (ov * gate[idx]) : (ov * (ls[c] + 1.f));
  X[idx] += v;
}

// ================================================================ launch
extern "C" void kernel_launch(void* const* d_in, const int* in_sizes, int n_in,
                              void* d_out, int out_size, void* d_ws, size_t ws_size,
                              hipStream_t stream) {
  const float* in_x   = (const float*)d_in[0];
  const float* times  = (const float*)d_in[1];
  const float* rotary = (const float*)d_in[2];
  const float* fwgt   = (const float*)d_in[3];
  const float* time_w = (const float*)d_in[4];
  const float* time_b = (const float*)d_in[5];
  const float* afw    = (const float*)d_in[6];
  const float* afb    = (const float*)d_in[7];
  const float* azw    = (const float*)d_in[8];
  const float* azb    = (const float*)d_in[9];
  const float* alng   = (const float*)d_in[10];
  const float* als    = (const float*)d_in[11];
  const float* armsg  = (const float*)d_in[12];
  const float* wqkv   = (const float*)d_in[13];
  const float* wout   = (const float*)d_in[14];
  const float* ffw    = (const float*)d_in[15];
  const float* ffb    = (const float*)d_in[16];
  const float* fzw    = (const float*)d_in[17];
  const float* fzb    = (const float*)d_in[18];
  const float* flng   = (const float*)d_in[19];
  const float* fls    = (const float*)d_in[20];
  const float* frmsg  = (const float*)d_in[21];
  const float* fw1    = (const float*)d_in[22];
  const float* fb1    = (const float*)d_in[23];
  const float* fw2    = (const float*)d_in[24];
  const float* fb2    = (const float*)d_in[25];
  const float* fing   = (const float*)d_in[26];
  const int*   mp     = (const int*)d_in[27];
  float* out = (float*)d_out;

  // workspace layout — total 212,697,088 B (< 218,644,480 B verified baseline footprint)
  char* p = (char*)d_ws;
  unsigned short* wT   = (unsigned short*)p;      p += 25165824;  // [3072][4096] bf16 max (fused film+gate)
  float* f_x           = (float*)p;               p += 16777216;
  float* f_ln          = (float*)p;               p += 16777216;
  float* f_o           = (float*)p;               p += 16777216;
  unsigned short* cond = (unsigned short*)p;      p += 33554432;  // [4096][4096] bf16
  unsigned short* hbf  = (unsigned short*)p;      p += 8388608;   // [4096][1024] bf16
  float* film          = (float*)p;               p += 33554432;  // [4096][2048] f32
  float* gate          = (float*)p;               p += 16777216;  // [4096][1024] f32
  char* arena          = p;                       p += 44908544;
  float* f_ismod       = (float*)p;               p += 16384;

  // arena liveness:
  //  attn phase: qkv [0,25165824) | vtg [25165824,33554432) | attno [33554432,41943040)
  //  ff phase:   ff1c [0,22364160) | mid [22364160,44908544)   (qkv/vtg/attno dead)
  //  cond phase: four [0,8650752)
  unsigned short* qkv    = (unsigned short*)arena;
  unsigned short* vtg    = (unsigned short*)(arena + 25165824);
  unsigned short* attno  = (unsigned short*)(arena + 33554432);
  float* ff1c            = (float*)arena;
  unsigned short* mid    = (unsigned short*)(arena + 22364160);
  unsigned short* four   = (unsigned short*)arena;

  auto gemm = [&](const unsigned short* A, const float* bias, const float* bias2,
                  void* C, void* C2, int K, int Nc, int mode, int out_bf, int mtiles) {
    mfma_gemm<<<dim3((Nc + 127) / 128, mtiles), 256, 0, stream>>>(
        A, wT, bias, bias2, C, C2, K, Nc, mode, out_bf);
  };
  auto transp = [&](const float* W, unsigned short* dst, int K, int N, int KP) {
    transpose_w<<<dim3(KP / 32, (N + 31) / 32), dim3(32, 8), 0, stream>>>(W, dst, K, N, KP);
  };

  // ---- conditioning ----
  fourier_kernel<<<ROWS_, 256, 0, stream>>>(times, fwgt, four);
  transp(time_w, wT, 1025, DCOND_, KF_);
  gemm(four, time_b, nullptr, cond, nullptr, KF_, DCOND_, 2, 1, 32);
  ismod_kernel<<<ROWS_ / 256, 256, 0, stream>>>(mp, f_ismod);
  hipMemcpyAsync(f_x, in_x, (size_t)ROWS_ * DIM_ * sizeof(float),
                 hipMemcpyDeviceToDevice, stream);

  for (int l = 0; l < 2; ++l) {
    // ---- attention block ----
    layernorm_kernel<<<ROWS_, 256, 0, stream>>>(f_x, f_ln);
    transp(afw + (size_t)l * DCOND_ * 2048, wT, DCOND_, 2048, DCOND_);
    transp(azw + (size_t)l * DCOND_ * 1024, wT + (size_t)2048 * DCOND_, DCOND_, 1024, DCOND_);
    gemm(cond, afb + l * 2048, azb + l * 1024, film, gate, DCOND_, 3072, 4, 0, 32);
    modulate_kernel<<<(ROWS_ * DIM_) / 256, 256, 0, stream>>>(f_ln, film, alng + l * 1024, f_ismod);
    rmsnorm_kernel<<<ROWS_, 256, 0, stream>>>(f_ln, armsg + l * 1024, hbf, nullptr);
    transp(wqkv + (size_t)l * 1024 * 3072, wT, 1024, 3072, 1024);
    gemm(hbf, nullptr, nullptr, qkv, nullptr, 1024, 3072, 0, 1, 32);
    rotary_kernel<<<(ROWS_ * 1024) / 256, 256, 0, stream>>>(qkv, rotary);
    vtrans_kernel<<<dim3(64, 2, 32), dim3(32, 8), 0, stream>>>(qkv, vtg);
    attn_kernel<<<dim3(32, 32), 256, 0, stream>>>(qkv, vtg, mp, attno);
    transp(wout + (size_t)l * 1024 * 1024, wT, 1024, 1024, 1024);
    gemm(attno, nullptr, nullptr, f_o, nullptr, 1024, 1024, 0, 0, 32);
    residual_kernel<<<(ROWS_ * DIM_) / 256, 256, 0, stream>>>(f_x, f_o, gate, als + l * 1024, f_ismod);

    // ---- feed-forward block ----
    layernorm_kernel<<<ROWS_, 256, 0, stream>>>(f_x, f_ln);
    transp(ffw + (size_t)l * DCOND_ * 2048, wT, DCOND_, 2048, DCOND_);
    transp(fzw + (size_t)l * DCOND_ * 1024, wT + (size_t)2048 * DCOND_, DCOND_, 1024, DCOND_);
    gemm(cond, ffb + l * 2048, fzb + l * 1024, film, gate, DCOND_, 3072, 4, 0, 32);
    modulate_kernel<<<(ROWS_ * DIM_) / 256, 256, 0, stream>>>(f_ln, film, flng + l * 1024, f_ismod);
    rmsnorm_kernel<<<ROWS_, 256, 0, stream>>>(f_ln, frmsg + l * 1024, hbf, nullptr);
    transp(fw1 + (size_t)l * 1024 * DFF1_, wT, 1024, DFF1_, 1024);
    for (int rc = 0; rc < 4; ++rc) {
      gemm(hbf + (size_t)rc * 1024 * 1024, fb1 + l * DFF1_, nullptr, ff1c, nullptr, 1024, DFF1_, 1, 0, 8);
      geglu_kernel<<<dim3((KM_ + 255) / 256, 1024), 256, 0, stream>>>(
          ff1c, mid + (size_t)rc * 1024 * KM_);
    }
    transp(fw2 + (size_t)l * DFF_ * 1024, wT, DFF_, 1024, KM_);
    gemm(mid, fb2 + l * 1024, nullptr, f_o, nullptr, KM_, 1024, 1, 0, 32);
    residual_kernel<<<(ROWS_ * DIM_) / 256, 256, 0, stream>>>(f_x, f_o, gate, fls + l * 1024, f_ismod);
  }

  // final rmsnorm -> fp32 out
  rmsnorm_kernel<<<ROWS_, 256, 0, stream>>>(f_x, fing, nullptr, out);
}

// Round 5
// 1802.319 us; speedup vs baseline: 1.4582x; 1.1401x over previous
//
#include <hip/hip_runtime.h>
#include <math.h>

#define B_      2
#define N_      2048
#define DIM_    1024
#define ROWS_   4096      // B*N
#define DCOND_  4096
#define DFF_    2730
#define DFF1_   5460
#define KF_     1056      // fourier K padded (1025 -> 1056)
#define KM_     2752      // geglu-mid K padded (2730 -> 2752)
#define NGL_    5504      // geglu-interleaved ff1 output cols (2*KM_)
#define SCALE_  0.125f
#define TWO_PI_ 6.28318530717958647692f

#define KSTR_   72        // K-tile LDS row stride (shorts)
#define VSTR_   72        // V^T-tile LDS row stride
#define PSTR_   68        // P-tile LDS row stride

typedef __attribute__((ext_vector_type(8))) short bfx8;   // 8 bf16 = 4 VGPR
typedef __attribute__((ext_vector_type(4))) float fx4;    // MFMA accum

__device__ __forceinline__ float b2f(unsigned short u) {
  return __uint_as_float(((unsigned)u) << 16);
}
__device__ __forceinline__ unsigned short f2b(float f) {  // RNE
  unsigned x = __float_as_uint(f);
  return (unsigned short)((x + 0x7FFF + ((x >> 16) & 1)) >> 16);
}

// DPP row-rotate (16-lane row) — pure-VALU cross-lane
template <int CTRL>
__device__ __forceinline__ float dppf(float v) {
  return __uint_as_float((unsigned)__builtin_amdgcn_update_dpp(
      0, (int)__float_as_uint(v), CTRL, 0xf, 0xf, true));
}
__device__ __forceinline__ float rowmax16(float v) {
  v = fmaxf(v, dppf<0x121>(v));
  v = fmaxf(v, dppf<0x122>(v));
  v = fmaxf(v, dppf<0x124>(v));
  v = fmaxf(v, dppf<0x128>(v));
  return v;
}
__device__ __forceinline__ float rowsum16(float v) {
  v += dppf<0x121>(v);
  v += dppf<0x122>(v);
  v += dppf<0x124>(v);
  v += dppf<0x128>(v);
  return v;
}

// ---------------------------------------------------------------- fourier -> bf16 [4096][1056], zero-padded
__global__ __launch_bounds__(256) void fourier_kernel(const float* __restrict__ times,
                                                      const float* __restrict__ fw,
                                                      unsigned short* __restrict__ F) {
  int r = blockIdx.x;
  float tv = times[r];
  unsigned short* Fr = F + (size_t)r * KF_;
  for (int c = threadIdx.x; c < KF_; c += 256) {
    float v;
    if (c == 0)          v = tv;
    else if (c <= 512)   v = sinf(tv * fw[c - 1] * TWO_PI_);
    else if (c <= 1024)  v = cosf(tv * fw[c - 513] * TWO_PI_);
    else                 v = 0.f;
    Fr[c] = f2b(v);
  }
}

// ---------------------------------------------------------------- weight transpose: W f32 [K][N] -> WT bf16 [N][KP]
__global__ __launch_bounds__(256) void transpose_w(const float* __restrict__ W,
                                                   unsigned short* __restrict__ WT,
                                                   int K, int N, int KP) {
  __shared__ float t[32][33];
  int tx = threadIdx.x, ty = threadIdx.y;    // 32 x 8
  int k0 = blockIdx.x * 32, n0 = blockIdx.y * 32;
#pragma unroll
  for (int i = 0; i < 4; ++i) {
    int k = k0 + ty + i * 8, n = n0 + tx;
    t[ty + i * 8][tx] = (k < K && n < N) ? W[(size_t)k * N + n] : 0.f;
  }
  __syncthreads();
#pragma unroll
  for (int i = 0; i < 4; ++i) {
    int n = n0 + ty + i * 8;
    if (n < N) WT[(size_t)n * KP + k0 + tx] = f2b(t[tx][ty + i * 8]);
  }
}

// ---------------------------------------------------------------- ff1 weight transpose, geglu-interleaved
// W f32 [1024][5460] -> WT bf16 [5504][1024]; dest row n' = group*32+w:
//   w<16 -> u-col group*16+w ; w>=16 -> g-col 2730+group*16+(w-16); pad rows zero.
__global__ __launch_bounds__(256) void transpose_w_geglu(const float* __restrict__ W,
                                                         unsigned short* __restrict__ WT) {
  __shared__ float t[32][33];
  int tx = threadIdx.x, ty = threadIdx.y;   // 32 x 8
  int k0 = blockIdx.x * 32;                 // source-row (K) tile
  int n0 = blockIdx.y * 32;                 // dest-row tile (exactly one 32-group)
  int group = n0 >> 5;
  int ucol = group * 16 + (tx & 15);
  int src = (tx < 16) ? ucol : (DFF_ + ucol);
  bool valid = ucol < DFF_;
#pragma unroll
  for (int i = 0; i < 4; ++i) {
    int k = k0 + ty + i * 8;
    t[ty + i * 8][tx] = valid ? W[(size_t)k * DFF1_ + src] : 0.f;
  }
  __syncthreads();
#pragma unroll
  for (int i = 0; i < 4; ++i) {
    int n = n0 + ty + i * 8;
    WT[(size_t)n * 1024 + k0 + tx] = f2b(t[tx][ty + i * 8]);
  }
}

// ---------------------------------------------------------------- V transpose: qkv v-part -> VT[bh][64 d][2048 n] bf16
__global__ __launch_bounds__(256) void vtrans_kernel(const unsigned short* __restrict__ QKV,
                                                     unsigned short* __restrict__ VT) {
  __shared__ unsigned short t[32][33];
  int bh = blockIdx.z;                      // 0..31
  int b = bh >> 4, h = bh & 15;
  int n0 = blockIdx.x * 32, d0 = blockIdx.y * 32;
  int tx = threadIdx.x, ty = threadIdx.y;   // 32 x 8
#pragma unroll
  for (int i = 0; i < 4; ++i) {
    int n = n0 + ty + i * 8;
    t[ty + i * 8][tx] = QKV[(size_t)(b * N_ + n) * 3072 + 2048 + h * 64 + d0 + tx];
  }
  __syncthreads();
#pragma unroll
  for (int i = 0; i < 4; ++i) {
    int d = d0 + ty + i * 8;
    VT[((size_t)bh * 64 + d) * N_ + n0 + tx] = t[tx][ty + i * 8];
  }
}

// ---------------------------------------------------------------- MFMA GEMM (global_load_lds width-16 staging, m97 structure)
// mode: 0 none, 1 bias, 2 bias+silu, 3 bias+sigmoid,
//       4 fused film+gate: col<2048 -> bias+linear -> (float*)Cout [stride 2048]
//                          col>=2048 -> bias2+sigmoid -> (float*)Cout2 [stride 1024]
//       5 geglu-interleaved: ni pairs (u,g) -> gelu(g)*u -> bf16 mid [stride KM_]
__global__ __launch_bounds__(256) void mfma_gemm(const unsigned short* __restrict__ A,
                                                 const unsigned short* __restrict__ BT,
                                                 const float* __restrict__ bias,
                                                 const float* __restrict__ bias2,
                                                 void* __restrict__ Cout,
                                                 void* __restrict__ Cout2,
                                                 int K, int Nc, int mode, int out_bf) {
  __shared__ unsigned short As[128 * 32];
  __shared__ unsigned short Bs[128 * 32];
  int tid = threadIdx.x;
  int wave = tid >> 6, lane = tid & 63;
  int bm = blockIdx.y * 128, bn = blockIdx.x * 128;
  int wm = (wave >> 1) * 64, wn = (wave & 1) * 64;
  int lr = lane >> 4, lc = lane & 15;
  fx4 acc[4][4];
#pragma unroll
  for (int i = 0; i < 4; ++i)
#pragma unroll
    for (int j = 0; j < 4; ++j) acc[i][j] = (fx4){0.f, 0.f, 0.f, 0.f};

  for (int k0 = 0; k0 < K; k0 += 32) {
#pragma unroll
    for (int i = 0; i < 2; ++i) {
      int c = tid + i * 256;
      int row = c >> 2, kc = (c & 3) * 8;
      __builtin_amdgcn_global_load_lds(
          (const __attribute__((address_space(1))) void*)(A + (size_t)(bm + row) * K + k0 + kc),
          (__attribute__((address_space(3))) void*)(&As[c * 8]), 16, 0, 0);
      __builtin_amdgcn_global_load_lds(
          (const __attribute__((address_space(1))) void*)(BT + (size_t)(bn + row) * K + k0 + kc),
          (__attribute__((address_space(3))) void*)(&Bs[c * 8]), 16, 0, 0);
    }
    __syncthreads();
    bfx8 af[4], bf[4];
#pragma unroll
    for (int mi = 0; mi < 4; ++mi)
      af[mi] = *(const bfx8*)&As[(wm + mi * 16 + lc) * 32 + lr * 8];
#pragma unroll
    for (int ni = 0; ni < 4; ++ni)
      bf[ni] = *(const bfx8*)&Bs[(wn + ni * 16 + lc) * 32 + lr * 8];
    __builtin_amdgcn_s_setprio(1);
#pragma unroll
    for (int mi = 0; mi < 4; ++mi)
#pragma unroll
      for (int ni = 0; ni < 4; ++ni)
        acc[mi][ni] = __builtin_amdgcn_mfma_f32_16x16x32_bf16(af[mi], bf[ni], acc[mi][ni], 0, 0, 0);
    __builtin_amdgcn_s_setprio(0);
    __syncthreads();
  }

  if (mode == 5) {
#pragma unroll
    for (int mi = 0; mi < 4; ++mi)
#pragma unroll
      for (int ni = 0; ni < 4; ni += 2) {
        int colu = bn + wn + ni * 16 + lc;          // 32-aligned base + lc
        int mc = (colu >> 5) * 16 + lc;             // mid column
        bool valid = mc < DFF_;
        float bu = valid ? bias[mc] : 0.f;
        float bg = valid ? bias[DFF_ + mc] : 0.f;
#pragma unroll
        for (int r = 0; r < 4; ++r) {
          int row = bm + wm + mi * 16 + lr * 4 + r;
          float u = acc[mi][ni][r] + bu;
          float gg = acc[mi][ni + 1][r] + bg;
          float ge = 0.5f * gg * (1.f + erff(gg * 0.70710678118654752440f));
          ((unsigned short*)Cout)[(size_t)row * KM_ + mc] = f2b(valid ? ge * u : 0.f);
        }
      }
    return;
  }
  if (mode == 4) {
#pragma unroll
    for (int mi = 0; mi < 4; ++mi)
#pragma unroll
      for (int ni = 0; ni < 4; ++ni) {
        int col = bn + wn + ni * 16 + lc;
        if (col < 2048) {
          float bv = bias[col];
#pragma unroll
          for (int r = 0; r < 4; ++r) {
            int row = bm + wm + mi * 16 + lr * 4 + r;
            ((float*)Cout)[(size_t)row * 2048 + col] = acc[mi][ni][r] + bv;
          }
        } else {
          int c2 = col - 2048;
          float bv = bias2[c2];
#pragma unroll
          for (int r = 0; r < 4; ++r) {
            int row = bm + wm + mi * 16 + lr * 4 + r;
            float v = acc[mi][ni][r] + bv;
            ((float*)Cout2)[(size_t)row * 1024 + c2] = 1.f / (1.f + __expf(-v));
          }
        }
      }
    return;
  }
#pragma unroll
  for (int mi = 0; mi < 4; ++mi) {
#pragma unroll
    for (int ni = 0; ni < 4; ++ni) {
      int col = bn + wn + ni * 16 + lc;
      if (col >= Nc) continue;
      float bv = (mode >= 1) ? bias[col] : 0.f;
#pragma unroll
      for (int r = 0; r < 4; ++r) {
        int row = bm + wm + mi * 16 + lr * 4 + r;
        float v = acc[mi][ni][r] + bv;
        if (mode == 2)      v = v / (1.f + __expf(-v));
        else if (mode == 3) v = 1.f / (1.f + __expf(-v));
        if (out_bf) ((unsigned short*)Cout)[(size_t)row * Nc + col] = f2b(v);
        else        ((float*)Cout)[(size_t)row * Nc + col] = v;
      }
    }
  }
}

// ---------------------------------------------------------------- ismod
__global__ __launch_bounds__(256) void ismod_kernel(const int* __restrict__ mp,
                                                    float* __restrict__ ismod) {
  int idx = blockIdx.x * 256 + threadIdx.x;
  int b = idx >> 11, n = idx & 2047;
  const int* p = mp + b * 6;
  bool m = false;
#pragma unroll
  for (int mi = 0; mi < 2; ++mi) {
    int off = p[mi * 3 + 1], len = p[mi * 3 + 2];
    m = m || ((n >= off) && (n < off + len));
  }
  ismod[idx] = m ? 1.f : 0.f;
}

// ---------------------------------------------------------------- fused [residual] + layernorm + modulate + rmsnorm -> bf16
__global__ __launch_bounds__(256) void fuse_pre_kernel(
    float* __restrict__ X, const float* __restrict__ O,
    const float* __restrict__ grs,   // residual gate (null => no residual)
    const float* __restrict__ ls,    // residual layerscale
    const float* __restrict__ film,  // [ROWS][2048] gamma|beta
    const float* __restrict__ lng,   // ln gamma (non-modality)
    const float* __restrict__ rg,    // rms gamma
    const float* __restrict__ ismod,
    unsigned short* __restrict__ Yb) {
  int r = blockIdx.x, tid = threadIdx.x;
  bool im = ismod[r] != 0.f;
  float xv[4];
  float s = 0.f, ss = 0.f;
#pragma unroll
  for (int k = 0; k < 4; ++k) {
    int c = tid + k * 256;
    size_t idx = (size_t)r * 1024 + c;
    float x = X[idx];
    if (grs) {
      float ov = O[idx];
      x += im ? ov * grs[idx] : ov * (ls[c] + 1.f);
      X[idx] = x;
    }
    xv[k] = x; s += x; ss += x * x;
  }
#pragma unroll
  for (int o = 32; o > 0; o >>= 1) { s += __shfl_down(s, o); ss += __shfl_down(ss, o); }
  __shared__ float shs[4], shss[4], sh2[4];
  int w = tid >> 6;
  if ((tid & 63) == 0) { shs[w] = s; shss[w] = ss; }
  __syncthreads();
  float mu = (shs[0] + shs[1] + shs[2] + shs[3]) * (1.f / DIM_);
  float var = (shss[0] + shss[1] + shss[2] + shss[3]) * (1.f / DIM_) - mu * mu;
  float rstd = rsqrtf(var + 1e-5f);
  float h[4]; float s2 = 0.f;
#pragma unroll
  for (int k = 0; k < 4; ++k) {
    int c = tid + k * 256;
    float hh = (xv[k] - mu) * rstd;
    hh = im ? hh * (film[(size_t)r * 2048 + c] + 1.f) + film[(size_t)r * 2048 + 1024 + c]
            : hh * (lng[c] + 1.f);
    h[k] = hh; s2 += hh * hh;
  }
#pragma unroll
  for (int o = 32; o > 0; o >>= 1) s2 += __shfl_down(s2, o);
  if ((tid & 63) == 0) sh2[w] = s2;
  __syncthreads();
  float tot = sh2[0] + sh2[1] + sh2[2] + sh2[3];
  float scale = 32.f / fmaxf(sqrtf(tot), 1e-12f);
#pragma unroll
  for (int k = 0; k < 4; ++k) {
    int c = tid + k * 256;
    Yb[(size_t)r * 1024 + c] = f2b(h[k] * scale * (rg[c] + 1.f));
  }
}

// ---------------------------------------------------------------- final residual + rmsnorm -> f32 out
__global__ __launch_bounds__(256) void rms_final_kernel(
    const float* __restrict__ X, const float* __restrict__ O,
    const float* __restrict__ grs, const float* __restrict__ ls,
    const float* __restrict__ ismod, const float* __restrict__ g,
    float* __restrict__ out) {
  int r = blockIdx.x, tid = threadIdx.x;
  bool im = ismod[r] != 0.f;
  float xv[4]; float ss = 0.f;
#pragma unroll
  for (int k = 0; k < 4; ++k) {
    int c = tid + k * 256;
    size_t idx = (size_t)r * 1024 + c;
    float ov = O[idx];
    float x = X[idx] + (im ? ov * grs[idx] : ov * (ls[c] + 1.f));
    xv[k] = x; ss += x * x;
  }
#pragma unroll
  for (int o = 32; o > 0; o >>= 1) ss += __shfl_down(ss, o);
  __shared__ float shss[4];
  int w = tid >> 6;
  if ((tid & 63) == 0) shss[w] = ss;
  __syncthreads();
  float tots = shss[0] + shss[1] + shss[2] + shss[3];
  float scale = 32.f / fmaxf(sqrtf(tots), 1e-12f);
#pragma unroll
  for (int k = 0; k < 4; ++k) {
    int c = tid + k * 256;
    out[(size_t)r * 1024 + c] = xv[k] * scale * (g[c] + 1.f);
  }
}

// ---------------------------------------------------------------- rope cos/sin table: [2048*64] -> (cos,sin) pairs
__global__ __launch_bounds__(256) void ropetab_kernel(const float* __restrict__ rot,
                                                      float* __restrict__ tab) {
  int i = blockIdx.x * 256 + threadIdx.x;   // 2048*64
  float f = rot[i];
  tab[2 * i]     = cosf(f);
  tab[2 * i + 1] = sinf(f);
}

// ---------------------------------------------------------------- rotary on bf16 qkv (q,k halves), table-driven
__global__ __launch_bounds__(256) void rotary_kernel(unsigned short* __restrict__ QKV,
                                                     const float* __restrict__ tab) {
  int idx = blockIdx.x * 256 + threadIdx.x;   // ROWS_*1024 pairs
  int r = idx >> 10;
  int c0 = (idx & 1023) * 2;                  // 0..2046
  float2 t2 = ((const float2*)tab)[(r & 2047) * 64 + (c0 & 63)];
  float cs = t2.x, sn = t2.y;
  unsigned* p = (unsigned*)(QKV + (size_t)r * 3072 + c0);
  unsigned v = *p;
  float x0 = b2f((unsigned short)(v & 0xFFFF));
  float x1 = b2f((unsigned short)(v >> 16));
  float y0 = x0 * cs - x1 * sn;
  float y1 = x1 * cs + x0 * sn;
  *p = (unsigned)f2b(y0) | ((unsigned)f2b(y1) << 16);
}

// ---------------------------------------------------------------- MFMA flash attention
__global__ __launch_bounds__(256) void attn_kernel(const unsigned short* __restrict__ QKV,
                                                   const unsigned short* __restrict__ VTg,
                                                   const int* __restrict__ mp,
                                                   unsigned short* __restrict__ O) {
  __shared__ unsigned short Ks[64 * KSTR_];     // [key][d]
  __shared__ unsigned short Vt[64 * VSTR_];     // [d][key]
  __shared__ unsigned short Ps[4][16 * PSTR_];  // per-wave P [row][key]
  int bh = blockIdx.y;
  int b = bh >> 4, h = bh & 15;
  int qb = 31 - blockIdx.x;                     // heavy blocks first
  int tid = threadIdx.x, wave = tid >> 6, lane = tid & 63;
  int lg = lane >> 4, ln = lane & 15;
  int off0 = mp[b * 6 + 1], end0 = off0 + mp[b * 6 + 2];
  int off1 = mp[b * 6 + 4], end1 = off1 + mp[b * 6 + 5];
  int qmin = qb * 64;
  int qmax = qmin + 63;

  int qrow = qb * 64 + wave * 16 + ln;
  bfx8 qf0 = *(const bfx8*)(QKV + (size_t)(b * N_ + qrow) * 3072 + h * 64 + lg * 8);
  bfx8 qf1 = *(const bfx8*)(QKV + (size_t)(b * N_ + qrow) * 3072 + h * 64 + 32 + lg * 8);

  fx4 od[4];
#pragma unroll
  for (int i = 0; i < 4; ++i) od[i] = (fx4){0.f, 0.f, 0.f, 0.f};
  float m_[4] = {-3.0e38f, -3.0e38f, -3.0e38f, -3.0e38f};
  float l_[4] = {0.f, 0.f, 0.f, 0.f};
  int ibase = qb * 64 + wave * 16 + lg * 4;

  for (int jt = 0; jt < 32; ++jt) {
    int j0 = jt * 64;
    if (!((j0 <= qmax) || (qmax >= off0 && j0 < end0) || (qmax >= off1 && j0 < end1))) continue;
    bool full = (j0 + 63 <= qmin) || (qmin >= off0 && j0 + 63 < end0)
             || (qmin >= off1 && j0 + 63 < end1);
    __syncthreads();
    for (int e = tid; e < 512; e += 256) {
      int jj = e >> 3, dc = (e & 7) * 8;
      *(bfx8*)&Ks[jj * KSTR_ + dc] =
          *(const bfx8*)(QKV + (size_t)(b * N_ + j0 + jj) * 3072 + 1024 + h * 64 + dc);
    }
    for (int e = tid; e < 512; e += 256) {
      int d = e >> 3, kc = (e & 7) * 8;
      *(bfx8*)&Vt[d * VSTR_ + kc] =
          *(const bfx8*)(VTg + ((size_t)bh * 64 + d) * N_ + j0 + kc);
    }
    __syncthreads();
    fx4 sf[4];
    __builtin_amdgcn_s_setprio(1);
#pragma unroll
    for (int kn = 0; kn < 4; ++kn) {
      fx4 a = (fx4){0.f, 0.f, 0.f, 0.f};
      bfx8 b0 = *(const bfx8*)&Ks[(kn * 16 + ln) * KSTR_ + lg * 8];
      bfx8 b1 = *(const bfx8*)&Ks[(kn * 16 + ln) * KSTR_ + 32 + lg * 8];
      a = __builtin_amdgcn_mfma_f32_16x16x32_bf16(qf0, b0, a, 0, 0, 0);
      a = __builtin_amdgcn_mfma_f32_16x16x32_bf16(qf1, b1, a, 0, 0, 0);
      sf[kn] = a;
    }
    __builtin_amdgcn_s_setprio(0);
    float sv[4][4];
#pragma unroll
    for (int kn = 0; kn < 4; ++kn)
#pragma unroll
      for (int reg = 0; reg < 4; ++reg) {
        float e2 = __expf(sf[kn][reg] * 0.005f);
        float r = __builtin_amdgcn_rcpf(e2 + 1.f);
        sv[kn][reg] = fmaf(-100.f, r, 50.f);
      }
    if (!full) {
#pragma unroll
      for (int kn = 0; kn < 4; ++kn) {
        int j = j0 + kn * 16 + ln;
#pragma unroll
        for (int reg = 0; reg < 4; ++reg) {
          int i = ibase + reg;
          bool ok = (i >= j) || (i >= off0 && j < end0) || (i >= off1 && j < end1);
          sv[kn][reg] = ok ? sv[kn][reg] : -1.0e30f;
        }
      }
    }
    float scl[4];
#pragma unroll
    for (int reg = 0; reg < 4; ++reg) {
      float tm = fmaxf(fmaxf(sv[0][reg], sv[1][reg]), fmaxf(sv[2][reg], sv[3][reg]));
      tm = rowmax16(tm);
      float mn = fmaxf(m_[reg], tm);
      scl[reg] = __expf(m_[reg] - mn);
      m_[reg] = mn;
    }
    float ts[4];
#pragma unroll
    for (int reg = 0; reg < 4; ++reg) {
      float t = 0.f;
#pragma unroll
      for (int kn = 0; kn < 4; ++kn) {
        float pp = __expf(sv[kn][reg] - m_[reg]);
        sv[kn][reg] = pp;
        t += pp;
      }
      ts[reg] = rowsum16(t);
    }
#pragma unroll
    for (int reg = 0; reg < 4; ++reg) l_[reg] = l_[reg] * scl[reg] + ts[reg];
#pragma unroll
    for (int kn = 0; kn < 4; ++kn)
#pragma unroll
      for (int reg = 0; reg < 4; ++reg)
        Ps[wave][(lg * 4 + reg) * PSTR_ + kn * 16 + ln] = f2b(sv[kn][reg]);
#pragma unroll
    for (int dn = 0; dn < 4; ++dn)
#pragma unroll
      for (int reg = 0; reg < 4; ++reg) od[dn][reg] *= scl[reg];
    bfx8 pf0 = *(const bfx8*)&Ps[wave][ln * PSTR_ + lg * 8];
    bfx8 pf1 = *(const bfx8*)&Ps[wave][ln * PSTR_ + 32 + lg * 8];
    __builtin_amdgcn_s_setprio(1);
#pragma unroll
    for (int dn = 0; dn < 4; ++dn) {
      bfx8 v0 = *(const bfx8*)&Vt[(dn * 16 + ln) * VSTR_ + lg * 8];
      bfx8 v1 = *(const bfx8*)&Vt[(dn * 16 + ln) * VSTR_ + 32 + lg * 8];
      od[dn] = __builtin_amdgcn_mfma_f32_16x16x32_bf16(pf0, v0, od[dn], 0, 0, 0);
      od[dn] = __builtin_amdgcn_mfma_f32_16x16x32_bf16(pf1, v1, od[dn], 0, 0, 0);
    }
    __builtin_amdgcn_s_setprio(0);
  }
#pragma unroll
  for (int reg = 0; reg < 4; ++reg) {
    float inv = 1.f / l_[reg];
    unsigned short* orow = O + (size_t)(b * N_ + ibase + reg) * 1024 + h * 64;
#pragma unroll
    for (int dn = 0; dn < 4; ++dn)
      orow[dn * 16 + ln] = f2b(od[dn][reg] * inv);
  }
}

// ================================================================ launch
extern "C" void kernel_launch(void* const* d_in, const int* in_sizes, int n_in,
                              void* d_out, int out_size, void* d_ws, size_t ws_size,
                              hipStream_t stream) {
  const float* in_x   = (const float*)d_in[0];
  const float* times  = (const float*)d_in[1];
  const float* rotary = (const float*)d_in[2];
  const float* fwgt   = (const float*)d_in[3];
  const float* time_w = (const float*)d_in[4];
  const float* time_b = (const float*)d_in[5];
  const float* afw    = (const float*)d_in[6];
  const float* afb    = (const float*)d_in[7];
  const float* azw    = (const float*)d_in[8];
  const float* azb    = (const float*)d_in[9];
  const float* alng   = (const float*)d_in[10];
  const float* als    = (const float*)d_in[11];
  const float* armsg  = (const float*)d_in[12];
  const float* wqkv   = (const float*)d_in[13];
  const float* wout   = (const float*)d_in[14];
  const float* ffw    = (const float*)d_in[15];
  const float* ffb    = (const float*)d_in[16];
  const float* fzw    = (const float*)d_in[17];
  const float* fzb    = (const float*)d_in[18];
  const float* flng   = (const float*)d_in[19];
  const float* fls    = (const float*)d_in[20];
  const float* frmsg  = (const float*)d_in[21];
  const float* fw1    = (const float*)d_in[22];
  const float* fb1    = (const float*)d_in[23];
  const float* fw2    = (const float*)d_in[24];
  const float* fb2    = (const float*)d_in[25];
  const float* fing   = (const float*)d_in[26];
  const int*   mp     = (const int*)d_in[27];
  float* out = (float*)d_out;

  // workspace layout — total 210,780,160 B (< 212,697,088 B verified round-3 footprint)
  char* p = (char*)d_ws;
  unsigned short* wT   = (unsigned short*)p;      p += 25165824;  // [3072][4096] bf16 max
  float* f_x           = (float*)p;               p += 16777216;
  float* f_o           = (float*)p;               p += 16777216;
  unsigned short* cond = (unsigned short*)p;      p += 33554432;  // [4096][4096] bf16
  unsigned short* hbf  = (unsigned short*)p;      p += 8388608;   // [4096][1024] bf16
  float* film          = (float*)p;               p += 33554432;  // [4096][2048] f32
  float* gateA         = (float*)p;               p += 16777216;  // [4096][1024] f32
  float* gateF         = (float*)p;               p += 16777216;  // [4096][1024] f32
  float* ropetab       = (float*)p;               p += 1048576;   // [2048*64] (cos,sin)
  char* arena          = p;                       p += 41943040;
  float* f_ismod       = (float*)p;               p += 16384;

  // arena liveness:
  //  cond phase: four [0, 8650752)
  //  attn phase: qkv [0,25165824) | vtg [25165824,33554432) | attno [33554432,41943040)
  //  ff phase:   mid [0,22544384)   (qkv/vtg/attno dead)
  unsigned short* qkv    = (unsigned short*)arena;
  unsigned short* vtg    = (unsigned short*)(arena + 25165824);
  unsigned short* attno  = (unsigned short*)(arena + 33554432);
  unsigned short* mid    = (unsigned short*)arena;
  unsigned short* four   = (unsigned short*)arena;

  auto gemm = [&](const unsigned short* A, const float* bias, const float* bias2,
                  void* C, void* C2, int K, int Nc, int mode, int out_bf, int mtiles) {
    mfma_gemm<<<dim3((Nc + 127) / 128, mtiles), 256, 0, stream>>>(
        A, wT, bias, bias2, C, C2, K, Nc, mode, out_bf);
  };
  auto transp = [&](const float* W, unsigned short* dst, int K, int N, int KP) {
    transpose_w<<<dim3(KP / 32, (N + 31) / 32), dim3(32, 8), 0, stream>>>(W, dst, K, N, KP);
  };

  // ---- conditioning ----
  fourier_kernel<<<ROWS_, 256, 0, stream>>>(times, fwgt, four);
  transp(time_w, wT, 1025, DCOND_, KF_);
  gemm(four, time_b, nullptr, cond, nullptr, KF_, DCOND_, 2, 1, 32);
  ismod_kernel<<<ROWS_ / 256, 256, 0, stream>>>(mp, f_ismod);
  ropetab_kernel<<<(2048 * 64) / 256, 256, 0, stream>>>(rotary, ropetab);
  hipMemcpyAsync(f_x, in_x, (size_t)ROWS_ * DIM_ * sizeof(float),
                 hipMemcpyDeviceToDevice, stream);

  for (int l = 0; l < 2; ++l) {
    // ---- attention films (cond-only) ----
    transp(afw + (size_t)l * DCOND_ * 2048, wT, DCOND_, 2048, DCOND_);
    transp(azw + (size_t)l * DCOND_ * 1024, wT + (size_t)2048 * DCOND_, DCOND_, 1024, DCOND_);
    gemm(cond, afb + l * 2048, azb + l * 1024, film, gateA, DCOND_, 3072, 4, 0, 32);
    // ---- pre-attn: [ff residual of l-1] + LN + modulate + rms -> hbf ----
    fuse_pre_kernel<<<ROWS_, 256, 0, stream>>>(
        f_x, f_o, (l > 0) ? gateF : nullptr, fls + (l - 1) * 1024,
        film, alng + l * 1024, armsg + l * 1024, f_ismod, hbf);
    // ---- attention ----
    transp(wqkv + (size_t)l * 1024 * 3072, wT, 1024, 3072, 1024);
    gemm(hbf, nullptr, nullptr, qkv, nullptr, 1024, 3072, 0, 1, 32);
    rotary_kernel<<<(ROWS_ * 1024) / 256, 256, 0, stream>>>(qkv, ropetab);
    vtrans_kernel<<<dim3(64, 2, 32), dim3(32, 8), 0, stream>>>(qkv, vtg);
    attn_kernel<<<dim3(32, 32), 256, 0, stream>>>(qkv, vtg, mp, attno);
    transp(wout + (size_t)l * 1024 * 1024, wT, 1024, 1024, 1024);
    gemm(attno, nullptr, nullptr, f_o, nullptr, 1024, 1024, 0, 0, 32);

    // ---- ff films (cond-only; safe: gateA still live, film consumed) ----
    transp(ffw + (size_t)l * DCOND_ * 2048, wT, DCOND_, 2048, DCOND_);
    transp(fzw + (size_t)l * DCOND_ * 1024, wT + (size_t)2048 * DCOND_, DCOND_, 1024, DCOND_);
    gemm(cond, ffb + l * 2048, fzb + l * 1024, film, gateF, DCOND_, 3072, 4, 0, 32);
    // ---- pre-ff: attn residual + LN + modulate + rms -> hbf ----
    fuse_pre_kernel<<<ROWS_, 256, 0, stream>>>(
        f_x, f_o, gateA, als + l * 1024,
        film, flng + l * 1024, frmsg + l * 1024, f_ismod, hbf);
    // ---- ff: geglu-fused ff1, then ff2 ----
    transpose_w_geglu<<<dim3(32, NGL_ / 32), dim3(32, 8), 0, stream>>>(
        fw1 + (size_t)l * 1024 * DFF1_, wT);
    gemm(hbf, fb1 + l * DFF1_, nullptr, mid, nullptr, 1024, NGL_, 5, 0, 32);
    transp(fw2 + (size_t)l * DFF_ * 1024, wT, DFF_, 1024, KM_);
    gemm(mid, fb2 + l * 1024, nullptr, f_o, nullptr, KM_, 1024, 1, 0, 32);
  }

  // final: ff residual (l=1) + rmsnorm -> fp32 out
  rms_final_kernel<<<ROWS_, 256, 0, stream>>>(
      f_x, f_o, gateF, fls + 1024, f_ismod, fing, out);
}

// Round 6
// 1652.232 us; speedup vs baseline: 1.5907x; 1.0908x over previous
//
#include <hip/hip_runtime.h>
#include <math.h>

#define B_      2
#define N_      2048
#define DIM_    1024
#define ROWS_   4096      // B*N
#define DCOND_  4096
#define DFF_    2730
#define DFF1_   5460
#define KF_     1056      // fourier K padded (1025 -> 1056)
#define KM_     2752      // geglu-mid K padded (2730 -> 2752)
#define NGL_    5504      // geglu-interleaved ff1 output cols (2*KM_)
#define SCALE_  0.125f
#define TWO_PI_ 6.28318530717958647692f

#define KSTR_   72        // K-tile LDS row stride (shorts)
#define VSTR_   72        // V^T-tile LDS row stride
#define PSTR_   68        // P-tile LDS row stride

typedef __attribute__((ext_vector_type(8))) short bfx8;   // 8 bf16 = 4 VGPR
typedef __attribute__((ext_vector_type(4))) float fx4;    // MFMA accum

__device__ __forceinline__ float b2f(unsigned short u) {
  return __uint_as_float(((unsigned)u) << 16);
}
__device__ __forceinline__ unsigned short f2b(float f) {  // RNE
  unsigned x = __float_as_uint(f);
  return (unsigned short)((x + 0x7FFF + ((x >> 16) & 1)) >> 16);
}

// modality-span tile check: any row in [bm, bm+128) (global row space) inside a span?
__device__ __forceinline__ bool tile_active(const int* mp, int bm) {
  int bb = bm >> 11;
  int r0 = bm & 2047, r1 = r0 + 128;
  int o0 = mp[bb * 6 + 1], e0 = o0 + mp[bb * 6 + 2];
  int o1 = mp[bb * 6 + 4], e1 = o1 + mp[bb * 6 + 5];
  return ((o0 < e0) && (r0 < e0) && (r1 > o0)) ||
         ((o1 < e1) && (r0 < e1) && (r1 > o1));
}

// DPP row-rotate (16-lane row) — pure-VALU cross-lane
template <int CTRL>
__device__ __forceinline__ float dppf(float v) {
  return __uint_as_float((unsigned)__builtin_amdgcn_update_dpp(
      0, (int)__float_as_uint(v), CTRL, 0xf, 0xf, true));
}
__device__ __forceinline__ float rowmax16(float v) {
  v = fmaxf(v, dppf<0x121>(v));
  v = fmaxf(v, dppf<0x122>(v));
  v = fmaxf(v, dppf<0x124>(v));
  v = fmaxf(v, dppf<0x128>(v));
  return v;
}
__device__ __forceinline__ float rowsum16(float v) {
  v += dppf<0x121>(v);
  v += dppf<0x122>(v);
  v += dppf<0x124>(v);
  v += dppf<0x128>(v);
  return v;
}

// ---------------------------------------------------------------- fourier -> bf16 [4096][1056], zero-padded
// rows whose 128-row tile has no modality row are skipped (cond GEMM skips those tiles).
__global__ __launch_bounds__(256) void fourier_kernel(const float* __restrict__ times,
                                                      const float* __restrict__ fw,
                                                      const int* __restrict__ mp,
                                                      unsigned short* __restrict__ F) {
  int r = blockIdx.x;
  if (!tile_active(mp, r & ~127)) return;
  float tv = times[r];
  unsigned short* Fr = F + (size_t)r * KF_;
  for (int c = threadIdx.x; c < KF_; c += 256) {
    float v;
    if (c == 0)          v = tv;
    else if (c <= 512)   v = sinf(tv * fw[c - 1] * TWO_PI_);
    else if (c <= 1024)  v = cosf(tv * fw[c - 513] * TWO_PI_);
    else                 v = 0.f;
    Fr[c] = f2b(v);
  }
}

// ---------------------------------------------------------------- weight transpose: W f32 [K][N] -> WT bf16 [N][KP]
__global__ __launch_bounds__(256) void transpose_w(const float* __restrict__ W,
                                                   unsigned short* __restrict__ WT,
                                                   int K, int N, int KP) {
  __shared__ float t[32][33];
  int tx = threadIdx.x, ty = threadIdx.y;    // 32 x 8
  int k0 = blockIdx.x * 32, n0 = blockIdx.y * 32;
#pragma unroll
  for (int i = 0; i < 4; ++i) {
    int k = k0 + ty + i * 8, n = n0 + tx;
    t[ty + i * 8][tx] = (k < K && n < N) ? W[(size_t)k * N + n] : 0.f;
  }
  __syncthreads();
#pragma unroll
  for (int i = 0; i < 4; ++i) {
    int n = n0 + ty + i * 8;
    if (n < N) WT[(size_t)n * KP + k0 + tx] = f2b(t[tx][ty + i * 8]);
  }
}

// ---------------------------------------------------------------- ff1 weight transpose, geglu-interleaved
// W f32 [1024][5460] -> WT bf16 [5504][1024]; dest row n' = group*32+w:
//   w<16 -> u-col group*16+w ; w>=16 -> g-col 2730+group*16+(w-16); pad rows zero.
__global__ __launch_bounds__(256) void transpose_w_geglu(const float* __restrict__ W,
                                                         unsigned short* __restrict__ WT) {
  __shared__ float t[32][33];
  int tx = threadIdx.x, ty = threadIdx.y;   // 32 x 8
  int k0 = blockIdx.x * 32;                 // source-row (K) tile
  int n0 = blockIdx.y * 32;                 // dest-row tile (exactly one 32-group)
  int group = n0 >> 5;
  int ucol = group * 16 + (tx & 15);
  int src = (tx < 16) ? ucol : (DFF_ + ucol);
  bool valid = ucol < DFF_;
#pragma unroll
  for (int i = 0; i < 4; ++i) {
    int k = k0 + ty + i * 8;
    t[ty + i * 8][tx] = valid ? W[(size_t)k * DFF1_ + src] : 0.f;
  }
  __syncthreads();
#pragma unroll
  for (int i = 0; i < 4; ++i) {
    int n = n0 + ty + i * 8;
    WT[(size_t)n * 1024 + k0 + tx] = f2b(t[tx][ty + i * 8]);
  }
}

// ---------------------------------------------------------------- V transpose: qkv v-part -> VT[bh][64 d][2048 n] bf16
__global__ __launch_bounds__(256) void vtrans_kernel(const unsigned short* __restrict__ QKV,
                                                     unsigned short* __restrict__ VT) {
  __shared__ unsigned short t[32][33];
  int bh = blockIdx.z;                      // 0..31
  int b = bh >> 4, h = bh & 15;
  int n0 = blockIdx.x * 32, d0 = blockIdx.y * 32;
  int tx = threadIdx.x, ty = threadIdx.y;   // 32 x 8
#pragma unroll
  for (int i = 0; i < 4; ++i) {
    int n = n0 + ty + i * 8;
    t[ty + i * 8][tx] = QKV[(size_t)(b * N_ + n) * 3072 + 2048 + h * 64 + d0 + tx];
  }
  __syncthreads();
#pragma unroll
  for (int i = 0; i < 4; ++i) {
    int d = d0 + ty + i * 8;
    VT[((size_t)bh * 64 + d) * N_ + n0 + tx] = t[tx][ty + i * 8];
  }
}

// ---------------------------------------------------------------- MFMA GEMM (global_load_lds width-16 staging, m97 structure)
// mode: 0 none, 1 bias, 2 bias+silu, 3 bias+sigmoid,
//       4 fused film+gate: col<2048 -> bias+linear -> (float*)Cout [stride 2048]
//                          col>=2048 -> bias2+sigmoid -> (float*)Cout2 [stride 1024]
//       5 geglu-interleaved: ni pairs (u,g) -> gelu(g)*u -> bf16 mid [stride KM_]
// skip: if non-null, M-tiles with no modality row early-exit (output never read there).
__global__ __launch_bounds__(256) void mfma_gemm(const unsigned short* __restrict__ A,
                                                 const unsigned short* __restrict__ BT,
                                                 const float* __restrict__ bias,
                                                 const float* __restrict__ bias2,
                                                 void* __restrict__ Cout,
                                                 void* __restrict__ Cout2,
                                                 const int* __restrict__ skip,
                                                 int K, int Nc, int mode, int out_bf) {
  __shared__ unsigned short As[128 * 32];
  __shared__ unsigned short Bs[128 * 32];
  int tid = threadIdx.x;
  int wave = tid >> 6, lane = tid & 63;
  int bm = blockIdx.y * 128, bn = blockIdx.x * 128;
  if (skip && !tile_active(skip, bm)) return;   // wave-uniform, before any barrier
  int wm = (wave >> 1) * 64, wn = (wave & 1) * 64;
  int lr = lane >> 4, lc = lane & 15;
  fx4 acc[4][4];
#pragma unroll
  for (int i = 0; i < 4; ++i)
#pragma unroll
    for (int j = 0; j < 4; ++j) acc[i][j] = (fx4){0.f, 0.f, 0.f, 0.f};

  for (int k0 = 0; k0 < K; k0 += 32) {
#pragma unroll
    for (int i = 0; i < 2; ++i) {
      int c = tid + i * 256;
      int row = c >> 2, kc = (c & 3) * 8;
      __builtin_amdgcn_global_load_lds(
          (const __attribute__((address_space(1))) void*)(A + (size_t)(bm + row) * K + k0 + kc),
          (__attribute__((address_space(3))) void*)(&As[c * 8]), 16, 0, 0);
      __builtin_amdgcn_global_load_lds(
          (const __attribute__((address_space(1))) void*)(BT + (size_t)(bn + row) * K + k0 + kc),
          (__attribute__((address_space(3))) void*)(&Bs[c * 8]), 16, 0, 0);
    }
    __syncthreads();
    bfx8 af[4], bf[4];
#pragma unroll
    for (int mi = 0; mi < 4; ++mi)
      af[mi] = *(const bfx8*)&As[(wm + mi * 16 + lc) * 32 + lr * 8];
#pragma unroll
    for (int ni = 0; ni < 4; ++ni)
      bf[ni] = *(const bfx8*)&Bs[(wn + ni * 16 + lc) * 32 + lr * 8];
    __builtin_amdgcn_s_setprio(1);
#pragma unroll
    for (int mi = 0; mi < 4; ++mi)
#pragma unroll
      for (int ni = 0; ni < 4; ++ni)
        acc[mi][ni] = __builtin_amdgcn_mfma_f32_16x16x32_bf16(af[mi], bf[ni], acc[mi][ni], 0, 0, 0);
    __builtin_amdgcn_s_setprio(0);
    __syncthreads();
  }

  if (mode == 5) {
#pragma unroll
    for (int mi = 0; mi < 4; ++mi)
#pragma unroll
      for (int ni = 0; ni < 4; ni += 2) {
        int colu = bn + wn + ni * 16 + lc;          // 32-aligned base + lc
        int mc = (colu >> 5) * 16 + lc;             // mid column
        bool valid = mc < DFF_;
        float bu = valid ? bias[mc] : 0.f;
        float bg = valid ? bias[DFF_ + mc] : 0.f;
#pragma unroll
        for (int r = 0; r < 4; ++r) {
          int row = bm + wm + mi * 16 + lr * 4 + r;
          float u = acc[mi][ni][r] + bu;
          float gg = acc[mi][ni + 1][r] + bg;
          float ge = 0.5f * gg * (1.f + erff(gg * 0.70710678118654752440f));
          ((unsigned short*)Cout)[(size_t)row * KM_ + mc] = f2b(valid ? ge * u : 0.f);
        }
      }
    return;
  }
  if (mode == 4) {
#pragma unroll
    for (int mi = 0; mi < 4; ++mi)
#pragma unroll
      for (int ni = 0; ni < 4; ++ni) {
        int col = bn + wn + ni * 16 + lc;
        if (col < 2048) {
          float bv = bias[col];
#pragma unroll
          for (int r = 0; r < 4; ++r) {
            int row = bm + wm + mi * 16 + lr * 4 + r;
            ((float*)Cout)[(size_t)row * 2048 + col] = acc[mi][ni][r] + bv;
          }
        } else {
          int c2 = col - 2048;
          float bv = bias2[c2];
#pragma unroll
          for (int r = 0; r < 4; ++r) {
            int row = bm + wm + mi * 16 + lr * 4 + r;
            float v = acc[mi][ni][r] + bv;
            ((float*)Cout2)[(size_t)row * 1024 + c2] = 1.f / (1.f + __expf(-v));
          }
        }
      }
    return;
  }
#pragma unroll
  for (int mi = 0; mi < 4; ++mi) {
#pragma unroll
    for (int ni = 0; ni < 4; ++ni) {
      int col = bn + wn + ni * 16 + lc;
      if (col >= Nc) continue;
      float bv = (mode >= 1) ? bias[col] : 0.f;
#pragma unroll
      for (int r = 0; r < 4; ++r) {
        int row = bm + wm + mi * 16 + lr * 4 + r;
        float v = acc[mi][ni][r] + bv;
        if (mode == 2)      v = v / (1.f + __expf(-v));
        else if (mode == 3) v = 1.f / (1.f + __expf(-v));
        if (out_bf) ((unsigned short*)Cout)[(size_t)row * Nc + col] = f2b(v);
        else        ((float*)Cout)[(size_t)row * Nc + col] = v;
      }
    }
  }
}

// ---------------------------------------------------------------- ismod
__global__ __launch_bounds__(256) void ismod_kernel(const int* __restrict__ mp,
                                                    float* __restrict__ ismod) {
  int idx = blockIdx.x * 256 + threadIdx.x;
  int b = idx >> 11, n = idx & 2047;
  const int* p = mp + b * 6;
  bool m = false;
#pragma unroll
  for (int mi = 0; mi < 2; ++mi) {
    int off = p[mi * 3 + 1], len = p[mi * 3 + 2];
    m = m || ((n >= off) && (n < off + len));
  }
  ismod[idx] = m ? 1.f : 0.f;
}

// ---------------------------------------------------------------- fused [residual] + layernorm + modulate + rmsnorm -> bf16
__global__ __launch_bounds__(256) void fuse_pre_kernel(
    float* __restrict__ X, const float* __restrict__ O,
    const float* __restrict__ grs,   // residual gate (null => no residual)
    const float* __restrict__ ls,    // residual layerscale
    const float* __restrict__ film,  // [ROWS][2048] gamma|beta
    const float* __restrict__ lng,   // ln gamma (non-modality)
    const float* __restrict__ rg,    // rms gamma
    const float* __restrict__ ismod,
    unsigned short* __restrict__ Yb) {
  int r = blockIdx.x, tid = threadIdx.x;
  bool im = ismod[r] != 0.f;
  float xv[4];
  float s = 0.f, ss = 0.f;
#pragma unroll
  for (int k = 0; k < 4; ++k) {
    int c = tid + k * 256;
    size_t idx = (size_t)r * 1024 + c;
    float x = X[idx];
    if (grs) {
      float ov = O[idx];
      x += im ? ov * grs[idx] : ov * (ls[c] + 1.f);
      X[idx] = x;
    }
    xv[k] = x; s += x; ss += x * x;
  }
#pragma unroll
  for (int o = 32; o > 0; o >>= 1) { s += __shfl_down(s, o); ss += __shfl_down(ss, o); }
  __shared__ float shs[4], shss[4], sh2[4];
  int w = tid >> 6;
  if ((tid & 63) == 0) { shs[w] = s; shss[w] = ss; }
  __syncthreads();
  float mu = (shs[0] + shs[1] + shs[2] + shs[3]) * (1.f / DIM_);
  float var = (shss[0] + shss[1] + shss[2] + shss[3]) * (1.f / DIM_) - mu * mu;
  float rstd = rsqrtf(var + 1e-5f);
  float h[4]; float s2 = 0.f;
#pragma unroll
  for (int k = 0; k < 4; ++k) {
    int c = tid + k * 256;
    float hh = (xv[k] - mu) * rstd;
    hh = im ? hh * (film[(size_t)r * 2048 + c] + 1.f) + film[(size_t)r * 2048 + 1024 + c]
            : hh * (lng[c] + 1.f);
    h[k] = hh; s2 += hh * hh;
  }
#pragma unroll
  for (int o = 32; o > 0; o >>= 1) s2 += __shfl_down(s2, o);
  if ((tid & 63) == 0) sh2[w] = s2;
  __syncthreads();
  float tot = sh2[0] + sh2[1] + sh2[2] + sh2[3];
  float scale = 32.f / fmaxf(sqrtf(tot), 1e-12f);
#pragma unroll
  for (int k = 0; k < 4; ++k) {
    int c = tid + k * 256;
    Yb[(size_t)r * 1024 + c] = f2b(h[k] * scale * (rg[c] + 1.f));
  }
}

// ---------------------------------------------------------------- final residual + rmsnorm -> f32 out
__global__ __launch_bounds__(256) void rms_final_kernel(
    const float* __restrict__ X, const float* __restrict__ O,
    const float* __restrict__ grs, const float* __restrict__ ls,
    const float* __restrict__ ismod, const float* __restrict__ g,
    float* __restrict__ out) {
  int r = blockIdx.x, tid = threadIdx.x;
  bool im = ismod[r] != 0.f;
  float xv[4]; float ss = 0.f;
#pragma unroll
  for (int k = 0; k < 4; ++k) {
    int c = tid + k * 256;
    size_t idx = (size_t)r * 1024 + c;
    float ov = O[idx];
    float x = X[idx] + (im ? ov * grs[idx] : ov * (ls[c] + 1.f));
    xv[k] = x; ss += x * x;
  }
#pragma unroll
  for (int o = 32; o > 0; o >>= 1) ss += __shfl_down(ss, o);
  __shared__ float shss[4];
  int w = tid >> 6;
  if ((tid & 63) == 0) shss[w] = ss;
  __syncthreads();
  float tots = shss[0] + shss[1] + shss[2] + shss[3];
  float scale = 32.f / fmaxf(sqrtf(tots), 1e-12f);
#pragma unroll
  for (int k = 0; k < 4; ++k) {
    int c = tid + k * 256;
    out[(size_t)r * 1024 + c] = xv[k] * scale * (g[c] + 1.f);
  }
}

// ---------------------------------------------------------------- rope cos/sin table: [2048*64] -> (cos,sin) pairs
__global__ __launch_bounds__(256) void ropetab_kernel(const float* __restrict__ rot,
                                                      float* __restrict__ tab) {
  int i = blockIdx.x * 256 + threadIdx.x;   // 2048*64
  float f = rot[i];
  tab[2 * i]     = cosf(f);
  tab[2 * i + 1] = sinf(f);
}

// ---------------------------------------------------------------- rotary on bf16 qkv (q,k halves), table-driven
__global__ __launch_bounds__(256) void rotary_kernel(unsigned short* __restrict__ QKV,
                                                     const float* __restrict__ tab) {
  int idx = blockIdx.x * 256 + threadIdx.x;   // ROWS_*1024 pairs
  int r = idx >> 10;
  int c0 = (idx & 1023) * 2;                  // 0..2046
  float2 t2 = ((const float2*)tab)[(r & 2047) * 64 + (c0 & 63)];
  float cs = t2.x, sn = t2.y;
  unsigned* p = (unsigned*)(QKV + (size_t)r * 3072 + c0);
  unsigned v = *p;
  float x0 = b2f((unsigned short)(v & 0xFFFF));
  float x1 = b2f((unsigned short)(v >> 16));
  float y0 = x0 * cs - x1 * sn;
  float y1 = x1 * cs + x0 * sn;
  *p = (unsigned)f2b(y0) | ((unsigned)f2b(y1) << 16);
}

// ---------------------------------------------------------------- MFMA flash attention
__global__ __launch_bounds__(256) void attn_kernel(const unsigned short* __restrict__ QKV,
                                                   const unsigned short* __restrict__ VTg,
                                                   const int* __restrict__ mp,
                                                   unsigned short* __restrict__ O) {
  __shared__ unsigned short Ks[64 * KSTR_];     // [key][d]
  __shared__ unsigned short Vt[64 * VSTR_];     // [d][key]
  __shared__ unsigned short Ps[4][16 * PSTR_];  // per-wave P [row][key]
  int bh = blockIdx.y;
  int b = bh >> 4, h = bh & 15;
  int qb = 31 - blockIdx.x;                     // heavy blocks first
  int tid = threadIdx.x, wave = tid >> 6, lane = tid & 63;
  int lg = lane >> 4, ln = lane & 15;
  int off0 = mp[b * 6 + 1], end0 = off0 + mp[b * 6 + 2];
  int off1 = mp[b * 6 + 4], end1 = off1 + mp[b * 6 + 5];
  int qmin = qb * 64;
  int qmax = qmin + 63;

  int qrow = qb * 64 + wave * 16 + ln;
  bfx8 qf0 = *(const bfx8*)(QKV + (size_t)(b * N_ + qrow) * 3072 + h * 64 + lg * 8);
  bfx8 qf1 = *(const bfx8*)(QKV + (size_t)(b * N_ + qrow) * 3072 + h * 64 + 32 + lg * 8);

  fx4 od[4];
#pragma unroll
  for (int i = 0; i < 4; ++i) od[i] = (fx4){0.f, 0.f, 0.f, 0.f};
  float m_[4] = {-3.0e38f, -3.0e38f, -3.0e38f, -3.0e38f};
  float l_[4] = {0.f, 0.f, 0.f, 0.f};
  int ibase = qb * 64 + wave * 16 + lg * 4;

  for (int jt = 0; jt < 32; ++jt) {
    int j0 = jt * 64;
    if (!((j0 <= qmax) || (qmax >= off0 && j0 < end0) || (qmax >= off1 && j0 < end1))) continue;
    bool full = (j0 + 63 <= qmin) || (qmin >= off0 && j0 + 63 < end0)
             || (qmin >= off1 && j0 + 63 < end1);
    __syncthreads();
    for (int e = tid; e < 512; e += 256) {
      int jj = e >> 3, dc = (e & 7) * 8;
      *(bfx8*)&Ks[jj * KSTR_ + dc] =
          *(const bfx8*)(QKV + (size_t)(b * N_ + j0 + jj) * 3072 + 1024 + h * 64 + dc);
    }
    for (int e = tid; e < 512; e += 256) {
      int d = e >> 3, kc = (e & 7) * 8;
      *(bfx8*)&Vt[d * VSTR_ + kc] =
          *(const bfx8*)(VTg + ((size_t)bh * 64 + d) * N_ + j0 + kc);
    }
    __syncthreads();
    fx4 sf[4];
    __builtin_amdgcn_s_setprio(1);
#pragma unroll
    for (int kn = 0; kn < 4; ++kn) {
      fx4 a = (fx4){0.f, 0.f, 0.f, 0.f};
      bfx8 b0 = *(const bfx8*)&Ks[(kn * 16 + ln) * KSTR_ + lg * 8];
      bfx8 b1 = *(const bfx8*)&Ks[(kn * 16 + ln) * KSTR_ + 32 + lg * 8];
      a = __builtin_amdgcn_mfma_f32_16x16x32_bf16(qf0, b0, a, 0, 0, 0);
      a = __builtin_amdgcn_mfma_f32_16x16x32_bf16(qf1, b1, a, 0, 0, 0);
      sf[kn] = a;
    }
    __builtin_amdgcn_s_setprio(0);
    float sv[4][4];
#pragma unroll
    for (int kn = 0; kn < 4; ++kn)
#pragma unroll
      for (int reg = 0; reg < 4; ++reg) {
        float e2 = __expf(sf[kn][reg] * 0.005f);
        float r = __builtin_amdgcn_rcpf(e2 + 1.f);
        sv[kn][reg] = fmaf(-100.f, r, 50.f);
      }
    if (!full) {
#pragma unroll
      for (int kn = 0; kn < 4; ++kn) {
        int j = j0 + kn * 16 + ln;
#pragma unroll
        for (int reg = 0; reg < 4; ++reg) {
          int i = ibase + reg;
          bool ok = (i >= j) || (i >= off0 && j < end0) || (i >= off1 && j < end1);
          sv[kn][reg] = ok ? sv[kn][reg] : -1.0e30f;
        }
      }
    }
    float scl[4];
#pragma unroll
    for (int reg = 0; reg < 4; ++reg) {
      float tm = fmaxf(fmaxf(sv[0][reg], sv[1][reg]), fmaxf(sv[2][reg], sv[3][reg]));
      tm = rowmax16(tm);
      float mn = fmaxf(m_[reg], tm);
      scl[reg] = __expf(m_[reg] - mn);
      m_[reg] = mn;
    }
    float ts[4];
#pragma unroll
    for (int reg = 0; reg < 4; ++reg) {
      float t = 0.f;
#pragma unroll
      for (int kn = 0; kn < 4; ++kn) {
        float pp = __expf(sv[kn][reg] - m_[reg]);
        sv[kn][reg] = pp;
        t += pp;
      }
      ts[reg] = rowsum16(t);
    }
#pragma unroll
    for (int reg = 0; reg < 4; ++reg) l_[reg] = l_[reg] * scl[reg] + ts[reg];
#pragma unroll
    for (int kn = 0; kn < 4; ++kn)
#pragma unroll
      for (int reg = 0; reg < 4; ++reg)
        Ps[wave][(lg * 4 + reg) * PSTR_ + kn * 16 + ln] = f2b(sv[kn][reg]);
#pragma unroll
    for (int dn = 0; dn < 4; ++dn)
#pragma unroll
      for (int reg = 0; reg < 4; ++reg) od[dn][reg] *= scl[reg];
    bfx8 pf0 = *(const bfx8*)&Ps[wave][ln * PSTR_ + lg * 8];
    bfx8 pf1 = *(const bfx8*)&Ps[wave][ln * PSTR_ + 32 + lg * 8];
    __builtin_amdgcn_s_setprio(1);
#pragma unroll
    for (int dn = 0; dn < 4; ++dn) {
      bfx8 v0 = *(const bfx8*)&Vt[(dn * 16 + ln) * VSTR_ + lg * 8];
      bfx8 v1 = *(const bfx8*)&Vt[(dn * 16 + ln) * VSTR_ + 32 + lg * 8];
      od[dn] = __builtin_amdgcn_mfma_f32_16x16x32_bf16(pf0, v0, od[dn], 0, 0, 0);
      od[dn] = __builtin_amdgcn_mfma_f32_16x16x32_bf16(pf1, v1, od[dn], 0, 0, 0);
    }
    __builtin_amdgcn_s_setprio(0);
  }
#pragma unroll
  for (int reg = 0; reg < 4; ++reg) {
    float inv = 1.f / l_[reg];
    unsigned short* orow = O + (size_t)(b * N_ + ibase + reg) * 1024 + h * 64;
#pragma unroll
    for (int dn = 0; dn < 4; ++dn)
      orow[dn * 16 + ln] = f2b(od[dn][reg] * inv);
  }
}

// ================================================================ launch
extern "C" void kernel_launch(void* const* d_in, const int* in_sizes, int n_in,
                              void* d_out, int out_size, void* d_ws, size_t ws_size,
                              hipStream_t stream) {
  const float* in_x   = (const float*)d_in[0];
  const float* times  = (const float*)d_in[1];
  const float* rotary = (const float*)d_in[2];
  const float* fwgt   = (const float*)d_in[3];
  const float* time_w = (const float*)d_in[4];
  const float* time_b = (const float*)d_in[5];
  const float* afw    = (const float*)d_in[6];
  const float* afb    = (const float*)d_in[7];
  const float* azw    = (const float*)d_in[8];
  const float* azb    = (const float*)d_in[9];
  const float* alng   = (const float*)d_in[10];
  const float* als    = (const float*)d_in[11];
  const float* armsg  = (const float*)d_in[12];
  const float* wqkv   = (const float*)d_in[13];
  const float* wout   = (const float*)d_in[14];
  const float* ffw    = (const float*)d_in[15];
  const float* ffb    = (const float*)d_in[16];
  const float* fzw    = (const float*)d_in[17];
  const float* fzb    = (const float*)d_in[18];
  const float* flng   = (const float*)d_in[19];
  const float* fls    = (const float*)d_in[20];
  const float* frmsg  = (const float*)d_in[21];
  const float* fw1    = (const float*)d_in[22];
  const float* fb1    = (const float*)d_in[23];
  const float* fw2    = (const float*)d_in[24];
  const float* fb2    = (const float*)d_in[25];
  const float* fing   = (const float*)d_in[26];
  const int*   mp     = (const int*)d_in[27];
  float* out = (float*)d_out;

  // workspace layout — total 210,780,160 B (unchanged from verified round-5)
  char* p = (char*)d_ws;
  unsigned short* wT   = (unsigned short*)p;      p += 25165824;  // [3072][4096] bf16 max
  float* f_x           = (float*)p;               p += 16777216;
  float* f_o           = (float*)p;               p += 16777216;
  unsigned short* cond = (unsigned short*)p;      p += 33554432;  // [4096][4096] bf16
  unsigned short* hbf  = (unsigned short*)p;      p += 8388608;   // [4096][1024] bf16
  float* film          = (float*)p;               p += 33554432;  // [4096][2048] f32
  float* gateA         = (float*)p;               p += 16777216;  // [4096][1024] f32
  float* gateF         = (float*)p;               p += 16777216;  // [4096][1024] f32
  float* ropetab       = (float*)p;               p += 1048576;   // [2048*64] (cos,sin)
  char* arena          = p;                       p += 41943040;
  float* f_ismod       = (float*)p;               p += 16384;

  // arena liveness:
  //  cond phase: four [0, 8650752)
  //  attn phase: qkv [0,25165824) | vtg [25165824,33554432) | attno [33554432,41943040)
  //  ff phase:   mid [0,22544384)   (qkv/vtg/attno dead)
  unsigned short* qkv    = (unsigned short*)arena;
  unsigned short* vtg    = (unsigned short*)(arena + 25165824);
  unsigned short* attno  = (unsigned short*)(arena + 33554432);
  unsigned short* mid    = (unsigned short*)arena;
  unsigned short* four   = (unsigned short*)arena;

  auto gemm = [&](const unsigned short* A, const float* bias, const float* bias2,
                  void* C, void* C2, const int* skip, int K, int Nc, int mode,
                  int out_bf, int mtiles) {
    mfma_gemm<<<dim3((Nc + 127) / 128, mtiles), 256, 0, stream>>>(
        A, wT, bias, bias2, C, C2, skip, K, Nc, mode, out_bf);
  };
  auto transp = [&](const float* W, unsigned short* dst, int K, int N, int KP) {
    transpose_w<<<dim3(KP / 32, (N + 31) / 32), dim3(32, 8), 0, stream>>>(W, dst, K, N, KP);
  };

  // ---- conditioning (cond only consumed by film/gate GEMMs on modality tiles) ----
  fourier_kernel<<<ROWS_, 256, 0, stream>>>(times, fwgt, mp, four);
  transp(time_w, wT, 1025, DCOND_, KF_);
  gemm(four, time_b, nullptr, cond, nullptr, mp, KF_, DCOND_, 2, 1, 32);
  ismod_kernel<<<ROWS_ / 256, 256, 0, stream>>>(mp, f_ismod);
  ropetab_kernel<<<(2048 * 64) / 256, 256, 0, stream>>>(rotary, ropetab);
  hipMemcpyAsync(f_x, in_x, (size_t)ROWS_ * DIM_ * sizeof(float),
                 hipMemcpyDeviceToDevice, stream);

  for (int l = 0; l < 2; ++l) {
    // ---- attention films (cond-only; modality tiles only) ----
    transp(afw + (size_t)l * DCOND_ * 2048, wT, DCOND_, 2048, DCOND_);
    transp(azw + (size_t)l * DCOND_ * 1024, wT + (size_t)2048 * DCOND_, DCOND_, 1024, DCOND_);
    gemm(cond, afb + l * 2048, azb + l * 1024, film, gateA, mp, DCOND_, 3072, 4, 0, 32);
    // ---- pre-attn: [ff residual of l-1] + LN + modulate + rms -> hbf ----
    fuse_pre_kernel<<<ROWS_, 256, 0, stream>>>(
        f_x, f_o, (l > 0) ? gateF : nullptr, fls + (l - 1) * 1024,
        film, alng + l * 1024, armsg + l * 1024, f_ismod, hbf);
    // ---- attention ----
    transp(wqkv + (size_t)l * 1024 * 3072, wT, 1024, 3072, 1024);
    gemm(hbf, nullptr, nullptr, qkv, nullptr, nullptr, 1024, 3072, 0, 1, 32);
    rotary_kernel<<<(ROWS_ * 1024) / 256, 256, 0, stream>>>(qkv, ropetab);
    vtrans_kernel<<<dim3(64, 2, 32), dim3(32, 8), 0, stream>>>(qkv, vtg);
    attn_kernel<<<dim3(32, 32), 256, 0, stream>>>(qkv, vtg, mp, attno);
    transp(wout + (size_t)l * 1024 * 1024, wT, 1024, 1024, 1024);
    gemm(attno, nullptr, nullptr, f_o, nullptr, nullptr, 1024, 1024, 0, 0, 32);

    // ---- ff films (cond-only; modality tiles only) ----
    transp(ffw + (size_t)l * DCOND_ * 2048, wT, DCOND_, 2048, DCOND_);
    transp(fzw + (size_t)l * DCOND_ * 1024, wT + (size_t)2048 * DCOND_, DCOND_, 1024, DCOND_);
    gemm(cond, ffb + l * 2048, fzb + l * 1024, film, gateF, mp, DCOND_, 3072, 4, 0, 32);
    // ---- pre-ff: attn residual + LN + modulate + rms -> hbf ----
    fuse_pre_kernel<<<ROWS_, 256, 0, stream>>>(
        f_x, f_o, gateA, als + l * 1024,
        film, flng + l * 1024, frmsg + l * 1024, f_ismod, hbf);
    // ---- ff: geglu-fused ff1, then ff2 ----
    transpose_w_geglu<<<dim3(32, NGL_ / 32), dim3(32, 8), 0, stream>>>(
        fw1 + (size_t)l * 1024 * DFF1_, wT);
    gemm(hbf, fb1 + l * DFF1_, nullptr, mid, nullptr, nullptr, 1024, NGL_, 5, 0, 32);
    transp(fw2 + (size_t)l * DFF_ * 1024, wT, DFF_, 1024, KM_);
    gemm(mid, fb2 + l * 1024, nullptr, f_o, nullptr, nullptr, KM_, 1024, 1, 0, 32);
  }

  // final: ff residual (l=1) + rmsnorm -> fp32 out
  rms_final_kernel<<<ROWS_, 256, 0, stream>>>(
      f_x, f_o, gateF, fls + 1024, f_ismod, fing, out);
}

// Round 8
// 1626.988 us; speedup vs baseline: 1.6154x; 1.0155x over previous
//
#include <hip/hip_runtime.h>
#include <math.h>

#define B_      2
#define N_      2048
#define DIM_    1024
#define ROWS_   4096      // B*N
#define DCOND_  4096
#define DFF_    2730
#define DFF1_   5460
#define KF_     1056      // fourier K padded (1025 -> 1056)
#define KM_     2752      // geglu-mid K padded (2730 -> 2752)
#define NGL_    5504      // geglu-interleaved ff1 output cols (2*KM_)
#define SCALE_  0.125f
#define TWO_PI_ 6.28318530717958647692f

#define KSTR_   72        // K-tile LDS row stride (shorts)
#define VSTR_   72        // V^T-tile LDS row stride
#define PSTR_   68        // P-tile LDS row stride

typedef __attribute__((ext_vector_type(8))) short bfx8;   // 8 bf16 = 4 VGPR
typedef __attribute__((ext_vector_type(4))) float fx4;    // MFMA accum

__device__ __forceinline__ float b2f(unsigned short u) {
  return __uint_as_float(((unsigned)u) << 16);
}
__device__ __forceinline__ unsigned short f2b(float f) {  // RNE
  unsigned x = __float_as_uint(f);
  return (unsigned short)((x + 0x7FFF + ((x >> 16) & 1)) >> 16);
}

// modality-span tile check: any row in [bm, bm+128) (global row space) inside a span?
__device__ __forceinline__ bool tile_active(const int* mp, int bm) {
  int bb = bm >> 11;
  int r0 = bm & 2047, r1 = r0 + 128;
  int o0 = mp[bb * 6 + 1], e0 = o0 + mp[bb * 6 + 2];
  int o1 = mp[bb * 6 + 4], e1 = o1 + mp[bb * 6 + 5];
  return ((o0 < e0) && (r0 < e0) && (r1 > o0)) ||
         ((o1 < e1) && (r0 < e1) && (r1 > o1));
}

// DPP row-rotate (16-lane row) — pure-VALU cross-lane
template <int CTRL>
__device__ __forceinline__ float dppf(float v) {
  return __uint_as_float((unsigned)__builtin_amdgcn_update_dpp(
      0, (int)__float_as_uint(v), CTRL, 0xf, 0xf, true));
}
__device__ __forceinline__ float rowmax16(float v) {
  v = fmaxf(v, dppf<0x121>(v));
  v = fmaxf(v, dppf<0x122>(v));
  v = fmaxf(v, dppf<0x124>(v));
  v = fmaxf(v, dppf<0x128>(v));
  return v;
}
__device__ __forceinline__ float rowsum16(float v) {
  v += dppf<0x121>(v);
  v += dppf<0x122>(v);
  v += dppf<0x124>(v);
  v += dppf<0x128>(v);
  return v;
}

// ---------------------------------------------------------------- fourier -> bf16 [4096][1056], zero-padded
// rows whose 128-row tile has no modality row are skipped (cond GEMM skips those tiles).
__global__ __launch_bounds__(256) void fourier_kernel(const float* __restrict__ times,
                                                      const float* __restrict__ fw,
                                                      const int* __restrict__ mp,
                                                      unsigned short* __restrict__ F) {
  int r = blockIdx.x;
  if (!tile_active(mp, r & ~127)) return;
  float tv = times[r];
  unsigned short* Fr = F + (size_t)r * KF_;
  for (int c = threadIdx.x; c < KF_; c += 256) {
    float v;
    if (c == 0)          v = tv;
    else if (c <= 512)   v = sinf(tv * fw[c - 1] * TWO_PI_);
    else if (c <= 1024)  v = cosf(tv * fw[c - 513] * TWO_PI_);
    else                 v = 0.f;
    Fr[c] = f2b(v);
  }
}

// ---------------------------------------------------------------- weight transpose: W f32 [K][N] -> WT bf16 [N][KP]
__global__ __launch_bounds__(256) void transpose_w(const float* __restrict__ W,
                                                   unsigned short* __restrict__ WT,
                                                   int K, int N, int KP) {
  __shared__ float t[32][33];
  int tx = threadIdx.x, ty = threadIdx.y;    // 32 x 8
  int k0 = blockIdx.x * 32, n0 = blockIdx.y * 32;
#pragma unroll
  for (int i = 0; i < 4; ++i) {
    int k = k0 + ty + i * 8, n = n0 + tx;
    t[ty + i * 8][tx] = (k < K && n < N) ? W[(size_t)k * N + n] : 0.f;
  }
  __syncthreads();
#pragma unroll
  for (int i = 0; i < 4; ++i) {
    int n = n0 + ty + i * 8;
    if (n < N) WT[(size_t)n * KP + k0 + tx] = f2b(t[tx][ty + i * 8]);
  }
}

// ---------------------------------------------------------------- ff1 weight transpose, geglu-interleaved
// W f32 [1024][5460] -> WT bf16 [5504][1024]; dest row n' = group*32+w:
//   w<16 -> u-col group*16+w ; w>=16 -> g-col 2730+group*16+(w-16); pad rows zero.
__global__ __launch_bounds__(256) void transpose_w_geglu(const float* __restrict__ W,
                                                         unsigned short* __restrict__ WT) {
  __shared__ float t[32][33];
  int tx = threadIdx.x, ty = threadIdx.y;   // 32 x 8
  int k0 = blockIdx.x * 32;                 // source-row (K) tile
  int n0 = blockIdx.y * 32;                 // dest-row tile (exactly one 32-group)
  int group = n0 >> 5;
  int ucol = group * 16 + (tx & 15);
  int src = (tx < 16) ? ucol : (DFF_ + ucol);
  bool valid = ucol < DFF_;
#pragma unroll
  for (int i = 0; i < 4; ++i) {
    int k = k0 + ty + i * 8;
    t[ty + i * 8][tx] = valid ? W[(size_t)k * DFF1_ + src] : 0.f;
  }
  __syncthreads();
#pragma unroll
  for (int i = 0; i < 4; ++i) {
    int n = n0 + ty + i * 8;
    WT[(size_t)n * 1024 + k0 + tx] = f2b(t[tx][ty + i * 8]);
  }
}

// ---------------------------------------------------------------- V transpose: qkv v-part -> VT[bh][64 d][2048 n] bf16
__global__ __launch_bounds__(256) void vtrans_kernel(const unsigned short* __restrict__ QKV,
                                                     unsigned short* __restrict__ VT) {
  __shared__ unsigned short t[32][33];
  int bh = blockIdx.z;                      // 0..31
  int b = bh >> 4, h = bh & 15;
  int n0 = blockIdx.x * 32, d0 = blockIdx.y * 32;
  int tx = threadIdx.x, ty = threadIdx.y;   // 32 x 8
#pragma unroll
  for (int i = 0; i < 4; ++i) {
    int n = n0 + ty + i * 8;
    t[ty + i * 8][tx] = QKV[(size_t)(b * N_ + n) * 3072 + 2048 + h * 64 + d0 + tx];
  }
  __syncthreads();
#pragma unroll
  for (int i = 0; i < 4; ++i) {
    int d = d0 + ty + i * 8;
    VT[((size_t)bh * 64 + d) * N_ + n0 + tx] = t[tx][ty + i * 8];
  }
}

// ---------------------------------------------------------------- MFMA GEMM (global_load_lds width-16 staging, m97 structure)
// mode: 0 none, 1 bias, 2 bias+silu, 3 bias+sigmoid,
//       4 fused film+gate: col<2048 -> bias+linear -> (float*)Cout [stride 2048]
//                          col>=2048 -> bias2+sigmoid -> (float*)Cout2 [stride 1024]
//       5 geglu-interleaved: ni pairs (u,g) -> gelu(g)*u -> bf16 mid [stride KM_]
// skip: if non-null, M-tiles with no modality row early-exit (output never read there).
__global__ __launch_bounds__(256) void mfma_gemm(const unsigned short* __restrict__ A,
                                                 const unsigned short* __restrict__ BT,
                                                 const float* __restrict__ bias,
                                                 const float* __restrict__ bias2,
                                                 void* __restrict__ Cout,
                                                 void* __restrict__ Cout2,
                                                 const int* __restrict__ skip,
                                                 int K, int Nc, int mode, int out_bf) {
  __shared__ unsigned short As[128 * 32];
  __shared__ unsigned short Bs[128 * 32];
  int tid = threadIdx.x;
  int wave = tid >> 6, lane = tid & 63;
  int bm = blockIdx.y * 128, bn = blockIdx.x * 128;
  if (skip && !tile_active(skip, bm)) return;   // wave-uniform, before any barrier
  int wm = (wave >> 1) * 64, wn = (wave & 1) * 64;
  int lr = lane >> 4, lc = lane & 15;
  fx4 acc[4][4];
#pragma unroll
  for (int i = 0; i < 4; ++i)
#pragma unroll
    for (int j = 0; j < 4; ++j) acc[i][j] = (fx4){0.f, 0.f, 0.f, 0.f};

  for (int k0 = 0; k0 < K; k0 += 32) {
#pragma unroll
    for (int i = 0; i < 2; ++i) {
      int c = tid + i * 256;
      int row = c >> 2, kc = (c & 3) * 8;
      __builtin_amdgcn_global_load_lds(
          (const __attribute__((address_space(1))) void*)(A + (size_t)(bm + row) * K + k0 + kc),
          (__attribute__((address_space(3))) void*)(&As[c * 8]), 16, 0, 0);
      __builtin_amdgcn_global_load_lds(
          (const __attribute__((address_space(1))) void*)(BT + (size_t)(bn + row) * K + k0 + kc),
          (__attribute__((address_space(3))) void*)(&Bs[c * 8]), 16, 0, 0);
    }
    __syncthreads();
    bfx8 af[4], bf[4];
#pragma unroll
    for (int mi = 0; mi < 4; ++mi)
      af[mi] = *(const bfx8*)&As[(wm + mi * 16 + lc) * 32 + lr * 8];
#pragma unroll
    for (int ni = 0; ni < 4; ++ni)
      bf[ni] = *(const bfx8*)&Bs[(wn + ni * 16 + lc) * 32 + lr * 8];
    __builtin_amdgcn_s_setprio(1);
#pragma unroll
    for (int mi = 0; mi < 4; ++mi)
#pragma unroll
      for (int ni = 0; ni < 4; ++ni)
        acc[mi][ni] = __builtin_amdgcn_mfma_f32_16x16x32_bf16(af[mi], bf[ni], acc[mi][ni], 0, 0, 0);
    __builtin_amdgcn_s_setprio(0);
    __syncthreads();
  }

  if (mode == 5) {
#pragma unroll
    for (int mi = 0; mi < 4; ++mi)
#pragma unroll
      for (int ni = 0; ni < 4; ni += 2) {
        int colu = bn + wn + ni * 16 + lc;          // 32-aligned base + lc
        int mc = (colu >> 5) * 16 + lc;             // mid column
        bool valid = mc < DFF_;
        float bu = valid ? bias[mc] : 0.f;
        float bg = valid ? bias[DFF_ + mc] : 0.f;
#pragma unroll
        for (int r = 0; r < 4; ++r) {
          int row = bm + wm + mi * 16 + lr * 4 + r;
          float u = acc[mi][ni][r] + bu;
          float gg = acc[mi][ni + 1][r] + bg;
          float ge = 0.5f * gg * (1.f + erff(gg * 0.70710678118654752440f));
          ((unsigned short*)Cout)[(size_t)row * KM_ + mc] = f2b(valid ? ge * u : 0.f);
        }
      }
    return;
  }
  if (mode == 4) {
#pragma unroll
    for (int mi = 0; mi < 4; ++mi)
#pragma unroll
      for (int ni = 0; ni < 4; ++ni) {
        int col = bn + wn + ni * 16 + lc;
        if (col < 2048) {
          float bv = bias[col];
#pragma unroll
          for (int r = 0; r < 4; ++r) {
            int row = bm + wm + mi * 16 + lr * 4 + r;
            ((float*)Cout)[(size_t)row * 2048 + col] = acc[mi][ni][r] + bv;
          }
        } else {
          int c2 = col - 2048;
          float bv = bias2[c2];
#pragma unroll
          for (int r = 0; r < 4; ++r) {
            int row = bm + wm + mi * 16 + lr * 4 + r;
            float v = acc[mi][ni][r] + bv;
            ((float*)Cout2)[(size_t)row * 1024 + c2] = 1.f / (1.f + __expf(-v));
          }
        }
      }
    return;
  }
#pragma unroll
  for (int mi = 0; mi < 4; ++mi) {
#pragma unroll
    for (int ni = 0; ni < 4; ++ni) {
      int col = bn + wn + ni * 16 + lc;
      if (col >= Nc) continue;
      float bv = (mode >= 1) ? bias[col] : 0.f;
#pragma unroll
      for (int r = 0; r < 4; ++r) {
        int row = bm + wm + mi * 16 + lr * 4 + r;
        float v = acc[mi][ni][r] + bv;
        if (mode == 2)      v = v / (1.f + __expf(-v));
        else if (mode == 3) v = 1.f / (1.f + __expf(-v));
        if (out_bf) ((unsigned short*)Cout)[(size_t)row * Nc + col] = f2b(v);
        else        ((float*)Cout)[(size_t)row * Nc + col] = v;
      }
    }
  }
}

// ---------------------------------------------------------------- ismod
__global__ __launch_bounds__(256) void ismod_kernel(const int* __restrict__ mp,
                                                    float* __restrict__ ismod) {
  int idx = blockIdx.x * 256 + threadIdx.x;
  int b = idx >> 11, n = idx & 2047;
  const int* p = mp + b * 6;
  bool m = false;
#pragma unroll
  for (int mi = 0; mi < 2; ++mi) {
    int off = p[mi * 3 + 1], len = p[mi * 3 + 2];
    m = m || ((n >= off) && (n < off + len));
  }
  ismod[idx] = m ? 1.f : 0.f;
}

// ---------------------------------------------------------------- fused [residual] + layernorm + modulate + rmsnorm -> bf16
__global__ __launch_bounds__(256) void fuse_pre_kernel(
    float* __restrict__ X, const float* __restrict__ O,
    const float* __restrict__ grs,   // residual gate (null => no residual)
    const float* __restrict__ ls,    // residual layerscale
    const float* __restrict__ film,  // [ROWS][2048] gamma|beta
    const float* __restrict__ lng,   // ln gamma (non-modality)
    const float* __restrict__ rg,    // rms gamma
    const float* __restrict__ ismod,
    unsigned short* __restrict__ Yb) {
  int r = blockIdx.x, tid = threadIdx.x;
  bool im = ismod[r] != 0.f;
  float xv[4];
  float s = 0.f, ss = 0.f;
#pragma unroll
  for (int k = 0; k < 4; ++k) {
    int c = tid + k * 256;
    size_t idx = (size_t)r * 1024 + c;
    float x = X[idx];
    if (grs) {
      float ov = O[idx];
      x += im ? ov * grs[idx] : ov * (ls[c] + 1.f);
      X[idx] = x;
    }
    xv[k] = x; s += x; ss += x * x;
  }
#pragma unroll
  for (int o = 32; o > 0; o >>= 1) { s += __shfl_down(s, o); ss += __shfl_down(ss, o); }
  __shared__ float shs[4], shss[4], sh2[4];
  int w = tid >> 6;
  if ((tid & 63) == 0) { shs[w] = s; shss[w] = ss; }
  __syncthreads();
  float mu = (shs[0] + shs[1] + shs[2] + shs[3]) * (1.f / DIM_);
  float var = (shss[0] + shss[1] + shss[2] + shss[3]) * (1.f / DIM_) - mu * mu;
  float rstd = rsqrtf(var + 1e-5f);
  float h[4]; float s2 = 0.f;
#pragma unroll
  for (int k = 0; k < 4; ++k) {
    int c = tid + k * 256;
    float hh = (xv[k] - mu) * rstd;
    hh = im ? hh * (film[(size_t)r * 2048 + c] + 1.f) + film[(size_t)r * 2048 + 1024 + c]
            : hh * (lng[c] + 1.f);
    h[k] = hh; s2 += hh * hh;
  }
#pragma unroll
  for (int o = 32; o > 0; o >>= 1) s2 += __shfl_down(s2, o);
  if ((tid & 63) == 0) sh2[w] = s2;
  __syncthreads();
  float tot = sh2[0] + sh2[1] + sh2[2] + sh2[3];
  float scale = 32.f / fmaxf(sqrtf(tot), 1e-12f);
#pragma unroll
  for (int k = 0; k < 4; ++k) {
    int c = tid + k * 256;
    Yb[(size_t)r * 1024 + c] = f2b(h[k] * scale * (rg[c] + 1.f));
  }
}

// ---------------------------------------------------------------- final residual + rmsnorm -> f32 out
__global__ __launch_bounds__(256) void rms_final_kernel(
    const float* __restrict__ X, const float* __restrict__ O,
    const float* __restrict__ grs, const float* __restrict__ ls,
    const float* __restrict__ ismod, const float* __restrict__ g,
    float* __restrict__ out) {
  int r = blockIdx.x, tid = threadIdx.x;
  bool im = ismod[r] != 0.f;
  float xv[4]; float ss = 0.f;
#pragma unroll
  for (int k = 0; k < 4; ++k) {
    int c = tid + k * 256;
    size_t idx = (size_t)r * 1024 + c;
    float ov = O[idx];
    float x = X[idx] + (im ? ov * grs[idx] : ov * (ls[c] + 1.f));
    xv[k] = x; ss += x * x;
  }
#pragma unroll
  for (int o = 32; o > 0; o >>= 1) ss += __shfl_down(ss, o);
  __shared__ float shss[4];
  int w = tid >> 6;
  if ((tid & 63) == 0) shss[w] = ss;
  __syncthreads();
  float tots = shss[0] + shss[1] + shss[2] + shss[3];
  float scale = 32.f / fmaxf(sqrtf(tots), 1e-12f);
#pragma unroll
  for (int k = 0; k < 4; ++k) {
    int c = tid + k * 256;
    out[(size_t)r * 1024 + c] = xv[k] * scale * (g[c] + 1.f);
  }
}

// ---------------------------------------------------------------- rope cos/sin table: [2048*64] -> (cos,sin) pairs
__global__ __launch_bounds__(256) void ropetab_kernel(const float* __restrict__ rot,
                                                      float* __restrict__ tab) {
  int i = blockIdx.x * 256 + threadIdx.x;   // 2048*64
  float f = rot[i];
  tab[2 * i]     = cosf(f);
  tab[2 * i + 1] = sinf(f);
}

// ---------------------------------------------------------------- rotary on bf16 qkv (q,k halves), table-driven
__global__ __launch_bounds__(256) void rotary_kernel(unsigned short* __restrict__ QKV,
                                                     const float* __restrict__ tab) {
  int idx = blockIdx.x * 256 + threadIdx.x;   // ROWS_*1024 pairs
  int r = idx >> 10;
  int c0 = (idx & 1023) * 2;                  // 0..2046
  float2 t2 = ((const float2*)tab)[(r & 2047) * 64 + (c0 & 63)];
  float cs = t2.x, sn = t2.y;
  unsigned* p = (unsigned*)(QKV + (size_t)r * 3072 + c0);
  unsigned v = *p;
  float x0 = b2f((unsigned short)(v & 0xFFFF));
  float x1 = b2f((unsigned short)(v >> 16));
  float y0 = x0 * cs - x1 * sn;
  float y1 = x1 * cs + x0 * sn;
  *p = (unsigned)f2b(y0) | ((unsigned)f2b(y1) << 16);
}

// ---------------------------------------------------------------- MFMA flash attention
// 4 waves/block, 16 q rows/wave. Active K/V tiles iterated via precomputed bitmask
// with register prefetch of the next tile: loads issued BEFORE compute (T14 split)
// so HBM latency hides under QK^T/softmax/PV.
__global__ __launch_bounds__(256) void attn_kernel(const unsigned short* __restrict__ QKV,
                                                   const unsigned short* __restrict__ VTg,
                                                   const int* __restrict__ mp,
                                                   unsigned short* __restrict__ O) {
  __shared__ unsigned short Ks[64 * KSTR_];     // [key][d]
  __shared__ unsigned short Vt[64 * VSTR_];     // [d][key]
  __shared__ unsigned short Ps[4][16 * PSTR_];  // per-wave P [row][key]
  int bh = blockIdx.y;
  int b = bh >> 4, h = bh & 15;
  int qb = 31 - blockIdx.x;                     // heavy blocks first
  int tid = threadIdx.x, wave = tid >> 6, lane = tid & 63;
  int lg = lane >> 4, ln = lane & 15;
  int off0 = mp[b * 6 + 1], end0 = off0 + mp[b * 6 + 2];
  int off1 = mp[b * 6 + 4], end1 = off1 + mp[b * 6 + 5];
  int qmin = qb * 64;
  int qmax = qmin + 63;

  int qrow = qb * 64 + wave * 16 + ln;
  bfx8 qf0 = *(const bfx8*)(QKV + (size_t)(b * N_ + qrow) * 3072 + h * 64 + lg * 8);
  bfx8 qf1 = *(const bfx8*)(QKV + (size_t)(b * N_ + qrow) * 3072 + h * 64 + 32 + lg * 8);

  // per-thread staging addresses: element e in {tid, tid+256}
  int e0 = tid, e1 = tid + 256;
  const unsigned short* Kp0 = QKV + (size_t)(b * N_ + (e0 >> 3)) * 3072 + 1024 + h * 64 + (e0 & 7) * 8;
  const unsigned short* Kp1 = QKV + (size_t)(b * N_ + (e1 >> 3)) * 3072 + 1024 + h * 64 + (e1 & 7) * 8;
  const unsigned short* Vp0 = VTg + ((size_t)bh * 64 + (e0 >> 3)) * N_ + (e0 & 7) * 8;
  const unsigned short* Vp1 = VTg + ((size_t)bh * 64 + (e1 >> 3)) * N_ + (e1 & 7) * 8;
  unsigned short* Kd0 = &Ks[(e0 >> 3) * KSTR_ + (e0 & 7) * 8];
  unsigned short* Kd1 = &Ks[(e1 >> 3) * KSTR_ + (e1 & 7) * 8];
  unsigned short* Vd0 = &Vt[(e0 >> 3) * VSTR_ + (e0 & 7) * 8];
  unsigned short* Vd1 = &Vt[(e1 >> 3) * VSTR_ + (e1 & 7) * 8];

  // active-tile bitmask (wave-uniform, SALU)
  unsigned actmask = 0;
  for (int t = 0; t < 32; ++t) {
    int j0 = t * 64;
    bool act = (j0 <= qmax) || (qmax >= off0 && j0 < end0) || (qmax >= off1 && j0 < end1);
    actmask |= act ? (1u << t) : 0u;
  }

  fx4 od[4];
#pragma unroll
  for (int i = 0; i < 4; ++i) od[i] = (fx4){0.f, 0.f, 0.f, 0.f};
  float m_[4] = {-3.0e38f, -3.0e38f, -3.0e38f, -3.0e38f};
  float l_[4] = {0.f, 0.f, 0.f, 0.f};
  int ibase = qb * 64 + wave * 16 + lg * 4;

  // prologue: prefetch first active tile (tile 0 always active: 0 <= qmax)
  int jt = __builtin_ctz(actmask);
  bfx8 kr0 = *(const bfx8*)(Kp0 + (size_t)(jt * 64) * 3072);
  bfx8 kr1 = *(const bfx8*)(Kp1 + (size_t)(jt * 64) * 3072);
  bfx8 vr0 = *(const bfx8*)(Vp0 + jt * 64);
  bfx8 vr1 = *(const bfx8*)(Vp1 + jt * 64);

  while (true) {
    int cur = jt;
    actmask &= actmask - 1;
    int nxt = actmask ? __builtin_ctz(actmask) : -1;
    int j0 = cur * 64;
    bool full = (j0 + 63 <= qmin) || (qmin >= off0 && j0 + 63 < end0)
             || (qmin >= off1 && j0 + 63 < end1);
    __syncthreads();                 // prior compute done reading LDS
    *(bfx8*)Kd0 = kr0; *(bfx8*)Kd1 = kr1;
    *(bfx8*)Vd0 = vr0; *(bfx8*)Vd1 = vr1;
    __syncthreads();                 // staged tile visible
    if (nxt >= 0) {                  // issue next-tile loads; latency hides under compute
      kr0 = *(const bfx8*)(Kp0 + (size_t)(nxt * 64) * 3072);
      kr1 = *(const bfx8*)(Kp1 + (size_t)(nxt * 64) * 3072);
      vr0 = *(const bfx8*)(Vp0 + nxt * 64);
      vr1 = *(const bfx8*)(Vp1 + nxt * 64);
    }
    // QK^T: S[16 q][64 key]
    fx4 sf[4];
    __builtin_amdgcn_s_setprio(1);
#pragma unroll
    for (int kn = 0; kn < 4; ++kn) {
      fx4 a = (fx4){0.f, 0.f, 0.f, 0.f};
      bfx8 b0 = *(const bfx8*)&Ks[(kn * 16 + ln) * KSTR_ + lg * 8];
      bfx8 b1 = *(const bfx8*)&Ks[(kn * 16 + ln) * KSTR_ + 32 + lg * 8];
      a = __builtin_amdgcn_mfma_f32_16x16x32_bf16(qf0, b0, a, 0, 0, 0);
      a = __builtin_amdgcn_mfma_f32_16x16x32_bf16(qf1, b1, a, 0, 0, 0);
      sf[kn] = a;
    }
    __builtin_amdgcn_s_setprio(0);
    // softcap: t = 50*tanh(sim/50) = 50 - 100/(exp(sim/25)+1); sim = raw*0.125
    float sv[4][4];
#pragma unroll
    for (int kn = 0; kn < 4; ++kn)
#pragma unroll
      for (int reg = 0; reg < 4; ++reg) {
        float e2 = __expf(sf[kn][reg] * 0.005f);
        float r = __builtin_amdgcn_rcpf(e2 + 1.f);
        sv[kn][reg] = fmaf(-100.f, r, 50.f);
      }
    if (!full) {
#pragma unroll
      for (int kn = 0; kn < 4; ++kn) {
        int j = j0 + kn * 16 + ln;
#pragma unroll
        for (int reg = 0; reg < 4; ++reg) {
          int i = ibase + reg;
          bool ok = (i >= j) || (i >= off0 && j < end0) || (i >= off1 && j < end1);
          sv[kn][reg] = ok ? sv[kn][reg] : -1.0e30f;
        }
      }
    }
    // online softmax per row: DPP row-rotate reduction across the 16 lanes/row
    float scl[4];
#pragma unroll
    for (int reg = 0; reg < 4; ++reg) {
      float tm = fmaxf(fmaxf(sv[0][reg], sv[1][reg]), fmaxf(sv[2][reg], sv[3][reg]));
      tm = rowmax16(tm);
      float mn = fmaxf(m_[reg], tm);
      scl[reg] = __expf(m_[reg] - mn);
      m_[reg] = mn;
    }
    float ts[4];
#pragma unroll
    for (int reg = 0; reg < 4; ++reg) {
      float t = 0.f;
#pragma unroll
      for (int kn = 0; kn < 4; ++kn) {
        float pp = __expf(sv[kn][reg] - m_[reg]);
        sv[kn][reg] = pp;
        t += pp;
      }
      ts[reg] = rowsum16(t);
    }
#pragma unroll
    for (int reg = 0; reg < 4; ++reg) l_[reg] = l_[reg] * scl[reg] + ts[reg];
    // P -> LDS (C-layout scatter), re-read as A-fragments
#pragma unroll
    for (int kn = 0; kn < 4; ++kn)
#pragma unroll
      for (int reg = 0; reg < 4; ++reg)
        Ps[wave][(lg * 4 + reg) * PSTR_ + kn * 16 + ln] = f2b(sv[kn][reg]);
    // rescale O
#pragma unroll
    for (int dn = 0; dn < 4; ++dn)
#pragma unroll
      for (int reg = 0; reg < 4; ++reg) od[dn][reg] *= scl[reg];
    bfx8 pf0 = *(const bfx8*)&Ps[wave][ln * PSTR_ + lg * 8];
    bfx8 pf1 = *(const bfx8*)&Ps[wave][ln * PSTR_ + 32 + lg * 8];
    __builtin_amdgcn_s_setprio(1);
#pragma unroll
    for (int dn = 0; dn < 4; ++dn) {
      bfx8 v0 = *(const bfx8*)&Vt[(dn * 16 + ln) * VSTR_ + lg * 8];
      bfx8 v1 = *(const bfx8*)&Vt[(dn * 16 + ln) * VSTR_ + 32 + lg * 8];
      od[dn] = __builtin_amdgcn_mfma_f32_16x16x32_bf16(pf0, v0, od[dn], 0, 0, 0);
      od[dn] = __builtin_amdgcn_mfma_f32_16x16x32_bf16(pf1, v1, od[dn], 0, 0, 0);
    }
    __builtin_amdgcn_s_setprio(0);
    if (nxt < 0) break;
    jt = nxt;
  }
#pragma unroll
  for (int reg = 0; reg < 4; ++reg) {
    float inv = 1.f / l_[reg];
    unsigned short* orow = O + (size_t)(b * N_ + ibase + reg) * 1024 + h * 64;
#pragma unroll
    for (int dn = 0; dn < 4; ++dn)
      orow[dn * 16 + ln] = f2b(od[dn][reg] * inv);
  }
}

// ================================================================ launch
extern "C" void kernel_launch(void* const* d_in, const int* in_sizes, int n_in,
                              void* d_out, int out_size, void* d_ws, size_t ws_size,
                              hipStream_t stream) {
  const float* in_x   = (const float*)d_in[0];
  const float* times  = (const float*)d_in[1];
  const float* rotary = (const float*)d_in[2];
  const float* fwgt   = (const float*)d_in[3];
  const float* time_w = (const float*)d_in[4];
  const float* time_b = (const float*)d_in[5];
  const float* afw    = (const float*)d_in[6];
  const float* afb    = (const float*)d_in[7];
  const float* azw    = (const float*)d_in[8];
  const float* azb    = (const float*)d_in[9];
  const float* alng   = (const float*)d_in[10];
  const float* als    = (const float*)d_in[11];
  const float* armsg  = (const float*)d_in[12];
  const float* wqkv   = (const float*)d_in[13];
  const float* wout   = (const float*)d_in[14];
  const float* ffw    = (const float*)d_in[15];
  const float* ffb    = (const float*)d_in[16];
  const float* fzw    = (const float*)d_in[17];
  const float* fzb    = (const float*)d_in[18];
  const float* flng   = (const float*)d_in[19];
  const float* fls    = (const float*)d_in[20];
  const float* frmsg  = (const float*)d_in[21];
  const float* fw1    = (const float*)d_in[22];
  const float* fb1    = (const float*)d_in[23];
  const float* fw2    = (const float*)d_in[24];
  const float* fb2    = (const float*)d_in[25];
  const float* fing   = (const float*)d_in[26];
  const int*   mp     = (const int*)d_in[27];
  float* out = (float*)d_out;

  // workspace layout — total 210,780,160 B (unchanged from verified round-5/6)
  char* p = (char*)d_ws;
  unsigned short* wT   = (unsigned short*)p;      p += 25165824;  // [3072][4096] bf16 max
  float* f_x           = (float*)p;               p += 16777216;
  float* f_o           = (float*)p;               p += 16777216;
  unsigned short* cond = (unsigned short*)p;      p += 33554432;  // [4096][4096] bf16
  unsigned short* hbf  = (unsigned short*)p;      p += 8388608;   // [4096][1024] bf16
  float* film          = (float*)p;               p += 33554432;  // [4096][2048] f32
  float* gateA         = (float*)p;               p += 16777216;  // [4096][1024] f32
  float* gateF         = (float*)p;               p += 16777216;  // [4096][1024] f32
  float* ropetab       = (float*)p;               p += 1048576;   // [2048*64] (cos,sin)
  char* arena          = p;                       p += 41943040;
  float* f_ismod       = (float*)p;               p += 16384;

  // arena liveness:
  //  cond phase: four [0, 8650752)
  //  attn phase: qkv [0,25165824) | vtg [25165824,33554432) | attno [33554432,41943040)
  //  ff phase:   mid [0,22544384)   (qkv/vtg/attno dead)
  unsigned short* qkv    = (unsigned short*)arena;
  unsigned short* vtg    = (unsigned short*)(arena + 25165824);
  unsigned short* attno  = (unsigned short*)(arena + 33554432);
  unsigned short* mid    = (unsigned short*)arena;
  unsigned short* four   = (unsigned short*)arena;

  auto gemm = [&](const unsigned short* A, const float* bias, const float* bias2,
                  void* C, void* C2, const int* skip, int K, int Nc, int mode,
                  int out_bf, int mtiles) {
    mfma_gemm<<<dim3((Nc + 127) / 128, mtiles), 256, 0, stream>>>(
        A, wT, bias, bias2, C, C2, skip, K, Nc, mode, out_bf);
  };
  auto transp = [&](const float* W, unsigned short* dst, int K, int N, int KP) {
    transpose_w<<<dim3(KP / 32, (N + 31) / 32), dim3(32, 8), 0, stream>>>(W, dst, K, N, KP);
  };

  // ---- conditioning (cond only consumed by film/gate GEMMs on modality tiles) ----
  fourier_kernel<<<ROWS_, 256, 0, stream>>>(times, fwgt, mp, four);
  transp(time_w, wT, 1025, DCOND_, KF_);
  gemm(four, time_b, nullptr, cond, nullptr, mp, KF_, DCOND_, 2, 1, 32);
  ismod_kernel<<<ROWS_ / 256, 256, 0, stream>>>(mp, f_ismod);
  ropetab_kernel<<<(2048 * 64) / 256, 256, 0, stream>>>(rotary, ropetab);
  hipMemcpyAsync(f_x, in_x, (size_t)ROWS_ * DIM_ * sizeof(float),
                 hipMemcpyDeviceToDevice, stream);

  for (int l = 0; l < 2; ++l) {
    // ---- attention films (cond-only; modality tiles only) ----
    transp(afw + (size_t)l * DCOND_ * 2048, wT, DCOND_, 2048, DCOND_);
    transp(azw + (size_t)l * DCOND_ * 1024, wT + (size_t)2048 * DCOND_, DCOND_, 1024, DCOND_);
    gemm(cond, afb + l * 2048, azb + l * 1024, film, gateA, mp, DCOND_, 3072, 4, 0, 32);
    // ---- pre-attn: [ff residual of l-1] + LN + modulate + rms -> hbf ----
    fuse_pre_kernel<<<ROWS_, 256, 0, stream>>>(
        f_x, f_o, (l > 0) ? gateF : nullptr, fls + (l - 1) * 1024,
        film, alng + l * 1024, armsg + l * 1024, f_ismod, hbf);
    // ---- attention ----
    transp(wqkv + (size_t)l * 1024 * 3072, wT, 1024, 3072, 1024);
    gemm(hbf, nullptr, nullptr, qkv, nullptr, nullptr, 1024, 3072, 0, 1, 32);
    rotary_kernel<<<(ROWS_ * 1024) / 256, 256, 0, stream>>>(qkv, ropetab);
    vtrans_kernel<<<dim3(64, 2, 32), dim3(32, 8), 0, stream>>>(qkv, vtg);
    attn_kernel<<<dim3(32, 32), 256, 0, stream>>>(qkv, vtg, mp, attno);
    transp(wout + (size_t)l * 1024 * 1024, wT, 1024, 1024, 1024);
    gemm(attno, nullptr, nullptr, f_o, nullptr, nullptr, 1024, 1024, 0, 0, 32);

    // ---- ff films (cond-only; modality tiles only) ----
    transp(ffw + (size_t)l * DCOND_ * 2048, wT, DCOND_, 2048, DCOND_);
    transp(fzw + (size_t)l * DCOND_ * 1024, wT + (size_t)2048 * DCOND_, DCOND_, 1024, DCOND_);
    gemm(cond, ffb + l * 2048, fzb + l * 1024, film, gateF, mp, DCOND_, 3072, 4, 0, 32);
    // ---- pre-ff: attn residual + LN + modulate + rms -> hbf ----
    fuse_pre_kernel<<<ROWS_, 256, 0, stream>>>(
        f_x, f_o, gateA, als + l * 1024,
        film, flng + l * 1024, frmsg + l * 1024, f_ismod, hbf);
    // ---- ff: geglu-fused ff1, then ff2 ----
    transpose_w_geglu<<<dim3(32, NGL_ / 32), dim3(32, 8), 0, stream>>>(
        fw1 + (size_t)l * 1024 * DFF1_, wT);
    gemm(hbf, fb1 + l * DFF1_, nullptr, mid, nullptr, nullptr, 1024, NGL_, 5, 0, 32);
    transp(fw2 + (size_t)l * DFF_ * 1024, wT, DFF_, 1024, KM_);
    gemm(mid, fb2 + l * 1024, nullptr, f_o, nullptr, nullptr, KM_, 1024, 1, 0, 32);
  }

  // final: ff residual (l=1) + rmsnorm -> fp32 out
  rms_final_kernel<<<ROWS_, 256, 0, stream>>>(
      f_x, f_o, gateF, fls + 1024, f_ismod, fing, out);
}